// Round 6
// baseline (13317.140 us; speedup 1.0000x reference)
//
#include <hip/hip_runtime.h>

// 2-layer LSTM (B=256,T=512,D=64,H=512) + FC, fp16 MFMA / fp32 accum.
// Grid 256 coop = 8 batch-groups x 32 hidden-slice blocks, 512 thr (8 waves),
// 1 blk/CU. Waves 0-3: recurrent path (poll, h-GEMM K=512, act, stage);
// waves 4-7: input projection one step ahead into parity LDS ring; wave 4
// publishes h(t-1). Handoff uses PROVEN sc1/IF semantics (round-4): relaxed
// agent atomics for hbuf/flags; publish order hbuf->vmcnt(0)->flag->oseq so
// the oseq HBM ack is off the critical path; hot poll (no s_sleep); h-GEMM
// issues all 32 A-loads at once (PD=16) -> single IF latency epoch.

typedef _Float16 f16;
typedef _Float16 f16x8 __attribute__((ext_vector_type(8)));
typedef _Float16 f16x4 __attribute__((ext_vector_type(4)));
typedef float    f32x4 __attribute__((ext_vector_type(4)));
typedef unsigned long long u64;

#define T_STEPS 512
#define NBATCH  256
#define DIN     64
#define NHID    512
#define NGRP    8
#define CBLK    32
#define NROWS   64   // gate rows per block: 4 gates x 16 hidden

__device__ __forceinline__ f32x4 mfma16(f16x8 a, f16x8 b, f32x4 c) {
    return __builtin_amdgcn_mfma_f32_16x16x32_f16(a, b, c, 0, 0, 0);
}

template<bool BYP>
__device__ __forceinline__ f16x8 ldA(const f16* p) {
    if constexpr (!BYP) {
        return *reinterpret_cast<const f16x8*>(p);
    } else {
        union { u64 u[2]; f16x8 v; } r;
        const u64* q = reinterpret_cast<const u64*>(p);
        r.u[0] = __hip_atomic_load(q,     __ATOMIC_RELAXED, __HIP_MEMORY_SCOPE_AGENT);
        r.u[1] = __hip_atomic_load(q + 1, __ATOMIC_RELAXED, __HIP_MEMORY_SCOPE_AGENT);
        return r.v;
    }
}

// NKS k-steps of K=32, two M-tiles. A direct from global, B from swizzled LDS.
// PD-deep prefetch ring (PD==NKS -> all loads issued up front, one latency
// epoch) + even/odd accumulators to break MFMA dep chains.
template<int NKS, int PD, bool BYP>
__device__ __forceinline__ void seg(const f16* a0p, const f16* a1p,
                                    const f16* Wl, int nbase, int xm, int q8, int ks0,
                                    f32x4& e0, f32x4& o0, f32x4& e1, f32x4& o1)
{
    f16x8 fa0[PD], fa1[PD];
#pragma unroll
    for (int p = 0; p < PD; ++p) {
        fa0[p] = ldA<BYP>(a0p + p * 32);
        fa1[p] = ldA<BYP>(a1p + p * 32);
    }
#pragma unroll
    for (int s = 0; s < NKS; ++s) {
        const int sl = s % PD;
        const int idx = nbase + ((((ks0 + s) * 32) + q8) ^ xm);
        const f16x8 bf = *reinterpret_cast<const f16x8*>(&Wl[idx]);
        if (s & 1) { o0 = mfma16(fa0[sl], bf, o0); o1 = mfma16(fa1[sl], bf, o1); }
        else       { e0 = mfma16(fa0[sl], bf, e0); e1 = mfma16(fa1[sl], bf, e1); }
        if (s + PD < NKS) {
            fa0[sl] = ldA<BYP>(a0p + (s + PD) * 32);
            fa1[sl] = ldA<BYP>(a1p + (s + PD) * 32);
        }
    }
}

__device__ __forceinline__ void act4(const f32x4 gv, const int gate,
                                     float (&cc)[4], float (&hh)[4])
{
#pragma unroll
    for (int jj = 0; jj < 4; ++jj) {
        const float v  = gv[jj];
        const float xs = (gate == 2) ? 2.0f * v : v;
        const float ee = exp2f(-1.44269504f * xs);
        const float sg = 1.0f / (1.0f + ee);
        const float a  = (gate == 2) ? (2.0f * sg - 1.0f) : sg;   // g uses tanh
        const float a1 = __shfl_xor(a, 1, 64);
        const float a2 = __shfl_xor(a, 2, 64);
        const float a3 = __shfl_xor(a, 3, 64);
        int d;
        float vi, vf, vg, vo;
        d = gate;     vi = d == 0 ? a : d == 1 ? a1 : d == 2 ? a2 : a3;
        d = gate ^ 1; vf = d == 0 ? a : d == 1 ? a1 : d == 2 ? a2 : a3;
        d = gate ^ 2; vg = d == 0 ? a : d == 1 ? a1 : d == 2 ? a2 : a3;
        d = gate ^ 3; vo = d == 0 ? a : d == 1 ? a1 : d == 2 ? a2 : a3;
        const float cn = vf * cc[jj] + vi * vg;
        cc[jj] = cn;
        const float e2 = exp2f(-2.88539008f * cn);   // tanh(c) = 2/(1+e^-2c)-1
        const float th = 2.0f / (1.0f + e2) - 1.0f;
        hh[jj] = vo * th;
    }
}

template<int KX, bool WSEQ, bool WLAST>
__global__ __launch_bounds__(512, 2) void lstm_layer(
    const f16*  __restrict__ in_seq,   // [B][T][KX] fp16
    const float* __restrict__ w_ih, const float* __restrict__ w_hh,
    const float* __restrict__ b_ih, const float* __restrict__ b_hh,
    f16* __restrict__ hbuf,            // [2][B][NHID] fp16 exchange (parity dbuf)
    f16* __restrict__ oseq,            // [B][T][NHID] fp16 (layer0) or null
    float* __restrict__ hlast,         // [B][NHID] f32 (layer1) or null
    unsigned* flags)                   // [T][NGRP][CBLK] flag lines (pre-zeroed)
{
    constexpr int KL  = KX + NHID;
    constexpr int NKX = KX / 32;
    constexpr int XPD = NKX < 10 ? NKX : 10;
    __shared__ f16   Wl[NROWS * KL];        // swizzled fp16 weights
    __shared__ float xring[2][NROWS][33];   // x-projection partials (padded)
    __shared__ f16   hstage[2][CBLK][16];   // h publish staging (parity)
    __shared__ float Lbias[NROWS];

    const int tid = threadIdx.x;
    const int g   = blockIdx.x & 7;
    const int jb  = blockIdx.x >> 3;

    // ---- stage weights (fp16, XOR-swizzled), rows n = 4*hid_l + gate ----
    for (int nr = 0; nr < NROWS; ++nr) {
        const int grow = (nr & 3) * NHID + jb * 16 + (nr >> 2);
        const float* sih = w_ih + (size_t)grow * KX;
        const float* shh = w_hh + (size_t)grow * NHID;
        for (int k = tid; k < KL; k += 512) {
            const float v = (k < KX) ? sih[k] : shh[k - KX];
            Wl[nr * KL + (k ^ ((nr & 7) << 3))] = (f16)v;
        }
    }
    if (tid < NROWS) {
        const int grow = (tid & 3) * NHID + jb * 16 + (tid >> 2);
        Lbias[tid] = b_ih[grow] + b_hh[grow];
    }
    __syncthreads();

    const int w    = tid >> 6;          // wave 0..7
    const int isH  = (w < 4);
    const int wr   = isH ? w : (w - 4);
    const int l    = tid & 63;
    const int col  = l & 15;
    const int q    = l >> 4;
    const int q8   = q << 3;
    const int n    = (wr << 4) | col;   // gate row 0..63
    const int gate = n & 3;
    const int hl   = n >> 2;
    const int bbase = g * CBLK;

    const float bias_n = Lbias[n];
    const int nbase = n * KL;
    const int xm    = (n & 7) << 3;

    const f16* px0 = in_seq + (size_t)(bbase + col) * T_STEPS * KX + q8;
    const f16* px1 = px0 + (size_t)16 * T_STEPS * KX;
    const int hoff0 = (bbase + col) * NHID + q8;
    const int hoff1 = hoff0 + 16 * NHID;

    float c0[4] = {0, 0, 0, 0}, c1[4] = {0, 0, 0, 0};

    auto xwork = [&](int tt) {
        f32x4 e0 = {bias_n, bias_n, bias_n, bias_n};
        f32x4 e1 = e0;
        f32x4 o0 = {0, 0, 0, 0}, o1 = {0, 0, 0, 0};
        seg<NKX, XPD, false>(px0, px1, Wl, nbase, xm, q8, 0, e0, o0, e1, o1);
        px0 += KX; px1 += KX;
        const f32x4 s0 = e0 + o0, s1 = e1 + o1;
        const int p = tt & 1;
#pragma unroll
        for (int jj = 0; jj < 4; ++jj) {
            xring[p][n][q * 4 + jj]      = s0[jj];
            xring[p][n][16 + q * 4 + jj] = s1[jj];
        }
    };

    // wave-4 publish of h(s): sc1 hbuf stores -> vmcnt(0) -> sc1 flag ->
    // oseq (HBM ack deliberately AFTER the flag; next kernel reads it).
    auto publish = [&](int s) {
        const int b = l >> 1, half = l & 1;
        union { u64 u[2]; f16x8 v; } pk;
        pk.v = *reinterpret_cast<const f16x8*>(&hstage[s & 1][b][half * 8]);
        f16* dst = hbuf + (s & 1) * (NBATCH * NHID)
                 + (size_t)(bbase + b) * NHID + jb * 16 + half * 8;
        u64* d64 = reinterpret_cast<u64*>(dst);
        __hip_atomic_store(d64,     pk.u[0], __ATOMIC_RELAXED, __HIP_MEMORY_SCOPE_AGENT);
        __hip_atomic_store(d64 + 1, pk.u[1], __ATOMIC_RELAXED, __HIP_MEMORY_SCOPE_AGENT);
        asm volatile("s_waitcnt vmcnt(0)" ::: "memory");
        if (l == 0)
            __hip_atomic_store(&flags[(size_t)s * (NGRP * CBLK) + g * CBLK + jb], 1u,
                               __ATOMIC_RELAXED, __HIP_MEMORY_SCOPE_AGENT);
        if (WSEQ) {
            f16* od = oseq + ((size_t)(bbase + b) * T_STEPS + s) * NHID
                    + jb * 16 + half * 8;
            *reinterpret_cast<f16x8*>(od) = pk.v;
        }
    };

    if (!isH) xwork(0);
    __syncthreads();

    for (int t = 0; t < T_STEPS; ++t) {
        if (isH) {
            const int p = t & 1;
            f32x4 e0, e1;
            f32x4 o0 = {0, 0, 0, 0}, o1 = {0, 0, 0, 0};
#pragma unroll
            for (int jj = 0; jj < 4; ++jj) {
                e0[jj] = xring[p][n][q * 4 + jj];
                e1[jj] = xring[p][n][16 + q * 4 + jj];
            }
            if (t > 0) {
                // hot wave-parallel poll of the 32 producer flags (sc1/IF)
                const unsigned* fb = flags + (size_t)(t - 1) * (NGRP * CBLK) + g * CBLK;
                unsigned spins = 0;
                for (;;) {
                    unsigned v = 1u;
                    if (l < CBLK)
                        v = __hip_atomic_load(fb + l, __ATOMIC_RELAXED,
                                              __HIP_MEMORY_SCOPE_AGENT);
                    if (__all(v != 0)) break;
                    if (++spins > (1u << 17)) break;   // fail finite, never hang
                }
                asm volatile("" ::: "memory");
                const f16* ph = hbuf + ((t - 1) & 1) * (NBATCH * NHID);
                // PD == NKS: all 32 A-loads issued before the first MFMA wait
                seg<16, 16, true>(ph + hoff0, ph + hoff1, Wl, nbase, xm, q8, NKX,
                                  e0, o0, e1, o1);
            }
            const f32x4 gv0 = e0 + o0;
            const f32x4 gv1 = e1 + o1;
            float h0v[4], h1v[4];
            act4(gv0, gate, c0, h0v);
            act4(gv1, gate, c1, h1v);
            if (gate == 0) {
#pragma unroll
                for (int jj = 0; jj < 4; ++jj) {
                    hstage[t & 1][q * 4 + jj][hl]      = (f16)h0v[jj];
                    hstage[t & 1][16 + q * 4 + jj][hl] = (f16)h1v[jj];
                }
                if (WLAST && t == T_STEPS - 1) {
#pragma unroll
                    for (int jj = 0; jj < 4; ++jj) {
                        hlast[(bbase + q * 4 + jj) * NHID + jb * 16 + hl]      = h0v[jj];
                        hlast[(bbase + 16 + q * 4 + jj) * NHID + jb * 16 + hl] = h1v[jj];
                    }
                }
            }
        } else {
            if (w == 4 && t > 0) publish(t - 1);
            if (t + 1 < T_STEPS) xwork(t + 1);
        }
        __syncthreads();
    }
    if (w == 4) publish(T_STEPS - 1);   // layer0 needs oseq[T-1]
}

__global__ void pack_x(const float* __restrict__ xin, f16* __restrict__ xp, int n4) {
    const int i = blockIdx.x * blockDim.x + threadIdx.x;
    if (i < n4) {
        const float4 v = reinterpret_cast<const float4*>(xin)[i];
        f16x4 o;
        o[0] = (f16)v.x; o[1] = (f16)v.y; o[2] = (f16)v.z; o[3] = (f16)v.w;
        reinterpret_cast<f16x4*>(xp)[i] = o;
    }
}

__global__ void fc_kernel(const float* __restrict__ hlast, const float* __restrict__ wfc,
                          const float* __restrict__ bfc, float* __restrict__ out) {
    const int wv = threadIdx.x >> 6, l = threadIdx.x & 63;
    const int b  = blockIdx.x * 4 + wv;
    const float* hr = hlast + b * NHID;
    float s = 0.f;
#pragma unroll
    for (int j = 0; j < 8; ++j) s += hr[l + 64 * j] * wfc[l + 64 * j];
#pragma unroll
    for (int off = 32; off; off >>= 1) s += __shfl_xor(s, off, 64);
    if (l == 0) out[b] = s + bfc[0];
}

extern "C" void kernel_launch(void* const* d_in, const int* in_sizes, int n_in,
                              void* d_out, int out_size, void* d_ws, size_t ws_size,
                              hipStream_t stream) {
    const float* x    = (const float*)d_in[0];
    const float* wih0 = (const float*)d_in[1];
    const float* whh0 = (const float*)d_in[2];
    const float* bih0 = (const float*)d_in[3];
    const float* bhh0 = (const float*)d_in[4];
    const float* wih1 = (const float*)d_in[5];
    const float* whh1 = (const float*)d_in[6];
    const float* bih1 = (const float*)d_in[7];
    const float* bhh1 = (const float*)d_in[8];
    const float* wfc  = (const float*)d_in[9];
    const float* bfc  = (const float*)d_in[10];
    float* out = (float*)d_out;

    char* ws = (char*)d_ws;
    const size_t XPK_ELEMS  = (size_t)NBATCH * T_STEPS * DIN;
    const size_t I1_ELEMS   = (size_t)NBATCH * T_STEPS * NHID;
    const size_t FLAG_ELEMS = (size_t)T_STEPS * NGRP * CBLK;    // 131072
    size_t off = 0;
    f16* xpk = (f16*)(ws + off);        off += XPK_ELEMS * 2;
    f16* i1  = (f16*)(ws + off);        off += I1_ELEMS * 2;        // 134 MB
    f16* hb0 = (f16*)(ws + off);        off += (size_t)2 * NBATCH * NHID * 2;
    f16* hb1 = (f16*)(ws + off);        off += (size_t)2 * NBATCH * NHID * 2;
    float* hlast = (float*)(ws + off);  off += (size_t)NBATCH * NHID * 4;
    unsigned* flg0 = (unsigned*)(ws + off); off += FLAG_ELEMS * 4;
    unsigned* flg1 = (unsigned*)(ws + off); off += FLAG_ELEMS * 4;

    // flags must be zero every call (graph replays!)
    hipMemsetAsync(flg0, 0, 2 * FLAG_ELEMS * 4, stream);

    pack_x<<<(int)((XPK_ELEMS / 4 + 255) / 256), 256, 0, stream>>>(x, xpk, (int)(XPK_ELEMS / 4));

    {
        const f16* in0 = xpk;
        f16* oseq0 = i1; float* hl0 = nullptr;
        void* a0[] = { (void*)&in0, (void*)&wih0, (void*)&whh0, (void*)&bih0,
                       (void*)&bhh0, (void*)&hb0, (void*)&oseq0, (void*)&hl0,
                       (void*)&flg0 };
        hipLaunchCooperativeKernel(lstm_layer<DIN, true, false>,
                                   dim3(256), dim3(512), a0, 0, stream);
    }
    {
        const f16* in1 = i1;
        f16* oseq1 = nullptr; float* hl1 = hlast;
        void* a1[] = { (void*)&in1, (void*)&wih1, (void*)&whh1, (void*)&bih1,
                       (void*)&bhh1, (void*)&hb1, (void*)&oseq1, (void*)&hl1,
                       (void*)&flg1 };
        hipLaunchCooperativeKernel(lstm_layer<NHID, false, true>,
                                   dim3(256), dim3(512), a1, 0, stream);
    }

    fc_kernel<<<64, 256, 0, stream>>>(hlast, wfc, bfc, out);
}

// Round 7
// 9630.779 us; speedup vs baseline: 1.3828x; 1.3828x over previous
//
#include <hip/hip_runtime.h>

// 2-layer LSTM (B=256,T=512,D=64,H=512) + FC, fp16 MFMA / fp32 accum.
// Grid 256 coop = 8 batch-groups x 32 hidden-slice blocks, 512 thr, 1 blk/CU.
// v7: weights live in VGPRs (16KB/wave B-frags, preloaded once); h(t-1) group
// tile staged ONCE per step into LDS by x-waves (4x IF-traffic cut); input
// sequence is time-major and double-buffer staged 2 steps ahead (T14 split).
// Handoff keeps the PROVEN sc1/IF protocol: relaxed agent atomics + vmcnt(0)
// + per-producer flag line + bounded wave-parallel poll.

typedef _Float16 f16;
typedef _Float16 f16x8 __attribute__((ext_vector_type(8)));
typedef _Float16 f16x4 __attribute__((ext_vector_type(4)));
typedef float    f32x4 __attribute__((ext_vector_type(4)));
typedef unsigned long long u64;

#define T_STEPS 512
#define NBATCH  256
#define DIN     64
#define NHID    512
#define NGRP    8
#define CBLK    32
#define NROWS   64   // gate rows per block: 4 gates x 16 hidden

__device__ __forceinline__ f32x4 mfma16(f16x8 a, f16x8 b, f32x4 c) {
    return __builtin_amdgcn_mfma_f32_16x16x32_f16(a, b, c, 0, 0, 0);
}

__device__ __forceinline__ f16x8 cvt8(const float* p) {
    const float4 v0 = *reinterpret_cast<const float4*>(p);
    const float4 v1 = *reinterpret_cast<const float4*>(p + 4);
    f16x8 r;
    r[0] = (f16)v0.x; r[1] = (f16)v0.y; r[2] = (f16)v0.z; r[3] = (f16)v0.w;
    r[4] = (f16)v1.x; r[5] = (f16)v1.y; r[6] = (f16)v1.z; r[7] = (f16)v1.w;
    return r;
}

__device__ __forceinline__ void act4(const f32x4 gv, const int gate,
                                     float (&cc)[4], float (&hh)[4])
{
#pragma unroll
    for (int jj = 0; jj < 4; ++jj) {
        const float v  = gv[jj];
        const float xs = (gate == 2) ? 2.0f * v : v;
        const float ee = exp2f(-1.44269504f * xs);
        const float sg = 1.0f / (1.0f + ee);
        const float a  = (gate == 2) ? (2.0f * sg - 1.0f) : sg;   // g uses tanh
        const float a1 = __shfl_xor(a, 1, 64);
        const float a2 = __shfl_xor(a, 2, 64);
        const float a3 = __shfl_xor(a, 3, 64);
        int d;
        float vi, vf, vg, vo;
        d = gate;     vi = d == 0 ? a : d == 1 ? a1 : d == 2 ? a2 : a3;
        d = gate ^ 1; vf = d == 0 ? a : d == 1 ? a1 : d == 2 ? a2 : a3;
        d = gate ^ 2; vg = d == 0 ? a : d == 1 ? a1 : d == 2 ? a2 : a3;
        d = gate ^ 3; vo = d == 0 ? a : d == 1 ? a1 : d == 2 ? a2 : a3;
        const float cn = vf * cc[jj] + vi * vg;
        cc[jj] = cn;
        const float e2 = exp2f(-2.88539008f * cn);   // tanh(c) = 2/(1+e^-2c)-1
        const float th = 2.0f / (1.0f + e2) - 1.0f;
        hh[jj] = vo * th;
    }
}

template<int KX, bool WSEQ, bool WLAST>
__global__ __launch_bounds__(512, 2) void lstm_layer(
    const f16*  __restrict__ in_seq,   // [T][B][KX] fp16, TIME-MAJOR
    const float* __restrict__ w_ih, const float* __restrict__ w_hh,
    const float* __restrict__ b_ih, const float* __restrict__ b_hh,
    f16* __restrict__ hbuf,            // [2][B][NHID] fp16 exchange (parity dbuf)
    f16* __restrict__ oseq,            // [T][B][NHID] fp16 (layer0) or null
    float* __restrict__ hlast,         // [B][NHID] f32 (layer1) or null
    unsigned* flags)                   // [T][NGRP][CBLK] flag lines (pre-zeroed)
{
    constexpr int NKX = KX / 32;   // x-GEMM k-slots
    constexpr int XCH = KX / 64;   // 16B chunks per coop lane for xT staging

    __shared__ f16   hT[CBLK * NHID];        // 32KB swizzled h(t-1) tile
    __shared__ f16   xT[2][CBLK * KX];       // raw input tiles, 2-deep pipeline
    __shared__ float xring[2][NROWS][33];    // x-projection partials (padded)
    __shared__ f16   hstage[2][CBLK][16];    // h publish staging (parity)
    __shared__ float Lbias[NROWS];

    const int tid = threadIdx.x;
    const int g   = blockIdx.x & 7;
    const int jb  = blockIdx.x >> 3;
    const int bbase = g * CBLK;

    if (tid < NROWS) {
        const int gr = (tid & 3) * NHID + jb * 16 + (tid >> 2);
        Lbias[tid] = b_ih[gr] + b_hh[gr];
    }

    const int w    = tid >> 6;          // wave 0..7
    const bool isH = (w < 4);
    const int wr   = isH ? w : (w - 4);
    const int l    = tid & 63;
    const int col  = l & 15;
    const int q    = l >> 4;
    const int q8   = q << 3;
    const int n    = (wr << 4) | col;   // gate row 0..63
    const int gate = n & 3;
    const int hl   = n >> 2;
    const int grow = (n & 3) * NHID + jb * 16 + (n >> 2);
    const int u    = wr * 64 + l;       // coop lane id 0..255 (x-waves)
    const int ub   = u >> 3;            // batch slot 0..31
    const int uc   = u & 7;             // chunk group 0..7

    // ---- weights -> registers (one-time): B-frag[s] = W[grow][32s+q8 .. +7]
    f16x8 BW[16];
    if (isH) {
        const float* src = w_hh + (size_t)grow * NHID + q8;
#pragma unroll
        for (int s = 0; s < 16; ++s) BW[s] = cvt8(src + s * 32);
    } else {
        const float* src = w_ih + (size_t)grow * KX + q8;
#pragma unroll
        for (int s = 0; s < NKX; ++s) BW[s] = cvt8(src + s * 32);
    }
    __syncthreads();
    const float bias_n = Lbias[n];

    float c0[4] = {0, 0, 0, 0}, c1[4] = {0, 0, 0, 0};

    // ---- x-tile staging (coop, coalesced, XOR-swizzled) ----
    auto stageLoad = [&](int tt, f16x8* stg) {
        const f16* src = in_seq + ((size_t)tt * NBATCH + bbase + ub) * KX + uc * (XCH * 8);
#pragma unroll
        for (int j = 0; j < XCH; ++j) stg[j] = *reinterpret_cast<const f16x8*>(src + j * 8);
    };
    auto stageWrite = [&](int tt, const f16x8* stg) {
        f16* dst = xT[tt & 1] + ub * KX;
#pragma unroll
        for (int j = 0; j < XCH; ++j)
            *reinterpret_cast<f16x8*>(dst + (((uc * XCH + j) ^ (ub & 7)) << 3)) = stg[j];
    };

    // ---- h-tile staging: sc1/IF loads (proven protocol) -> swizzled LDS ----
    auto hTload = [&](int par) {
        const u64* src = reinterpret_cast<const u64*>(
            hbuf + (size_t)par * (NBATCH * NHID) + (size_t)(bbase + ub) * NHID) + uc * 16;
        u64 tmp[16];
#pragma unroll
        for (int j = 0; j < 8; ++j) {
            tmp[2*j]   = __hip_atomic_load(src + 2*j,   __ATOMIC_RELAXED, __HIP_MEMORY_SCOPE_AGENT);
            tmp[2*j+1] = __hip_atomic_load(src + 2*j+1, __ATOMIC_RELAXED, __HIP_MEMORY_SCOPE_AGENT);
        }
        f16* dst = hT + ub * NHID;
#pragma unroll
        for (int j = 0; j < 8; ++j) {
            union { u64 a[2]; f16x8 v; } r;
            r.a[0] = tmp[2*j]; r.a[1] = tmp[2*j+1];
            *reinterpret_cast<f16x8*>(dst + (((uc * 8 + j) ^ (ub & 7)) << 3)) = r.v;
        }
    };

    // ---- x-projection of step tt from xT (A:LDS, B:regs) -> xring ----
    auto xwork = [&](int tt) {
        f32x4 e0 = {bias_n, bias_n, bias_n, bias_n}, e1 = e0;
        f32x4 o0 = {0, 0, 0, 0}, o1 = o0;
        const f16* xp = xT[tt & 1];
#pragma unroll
        for (int s = 0; s < NKX; ++s) {
            const int ch = ((q + 4 * s) ^ (col & 7)) << 3;
            const f16x8 a0 = *reinterpret_cast<const f16x8*>(xp + col * KX + ch);
            const f16x8 a1 = *reinterpret_cast<const f16x8*>(xp + (col + 16) * KX + ch);
            if (s & 1) { o0 = mfma16(a0, BW[s], o0); o1 = mfma16(a1, BW[s], o1); }
            else       { e0 = mfma16(a0, BW[s], e0); e1 = mfma16(a1, BW[s], e1); }
        }
        const f32x4 s0 = e0 + o0, s1 = e1 + o1;
        const int p = tt & 1;
#pragma unroll
        for (int jj = 0; jj < 4; ++jj) {
            xring[p][n][q * 4 + jj]      = s0[jj];
            xring[p][n][16 + q * 4 + jj] = s1[jj];
        }
    };

    // ---- recurrent GEMM K=512 (A: LDS hT, B: regs) ----
    auto hseg = [&](f32x4& e0, f32x4& o0, f32x4& e1, f32x4& o1) {
#pragma unroll
        for (int s = 0; s < 16; ++s) {
            const int ch = ((q + 4 * s) ^ (col & 7)) << 3;
            const f16x8 a0 = *reinterpret_cast<const f16x8*>(hT + col * NHID + ch);
            const f16x8 a1 = *reinterpret_cast<const f16x8*>(hT + (col + 16) * NHID + ch);
            if (s & 1) { o0 = mfma16(a0, BW[s], o0); o1 = mfma16(a1, BW[s], o1); }
            else       { e0 = mfma16(a0, BW[s], e0); e1 = mfma16(a1, BW[s], e1); }
        }
    };

    // ---- wave-4 publish of h(s): sc1 stores -> vmcnt(0) -> flag -> oseq ----
    auto publish = [&](int s) {
        const int b = l >> 1, half = l & 1;
        union { u64 a[2]; f16x8 v; } pk;
        pk.v = *reinterpret_cast<const f16x8*>(&hstage[s & 1][b][half * 8]);
        u64* d64 = reinterpret_cast<u64*>(
            hbuf + (size_t)(s & 1) * (NBATCH * NHID) + (size_t)(bbase + b) * NHID + jb * 16 + half * 8);
        __hip_atomic_store(d64,     pk.a[0], __ATOMIC_RELAXED, __HIP_MEMORY_SCOPE_AGENT);
        __hip_atomic_store(d64 + 1, pk.a[1], __ATOMIC_RELAXED, __HIP_MEMORY_SCOPE_AGENT);
        asm volatile("s_waitcnt vmcnt(0)" ::: "memory");
        if (l == 0)
            __hip_atomic_store(&flags[(size_t)s * (NGRP * CBLK) + g * CBLK + jb], 1u,
                               __ATOMIC_RELAXED, __HIP_MEMORY_SCOPE_AGENT);
        if (WSEQ) {
            f16* od = oseq + ((size_t)s * NBATCH + bbase + b) * NHID + jb * 16 + half * 8;
            *reinterpret_cast<f16x8*>(od) = pk.v;   // plain store, off critical path
        }
    };

    auto poll = [&](int s) {
        const unsigned* fb = flags + (size_t)s * (NGRP * CBLK) + g * CBLK;
        unsigned spins = 0;
        for (;;) {
            unsigned v = 1u;
            if (l < CBLK)
                v = __hip_atomic_load(fb + l, __ATOMIC_RELAXED, __HIP_MEMORY_SCOPE_AGENT);
            if (__all(v != 0)) break;
            __builtin_amdgcn_s_sleep(2);
            if (++spins > (1u << 17)) break;   // fail finite, never hang
        }
        asm volatile("" ::: "memory");
    };

    // ---- prologue: fill xT pipeline + xring[0] ----
    if (!isH) { f16x8 s0[XCH]; stageLoad(0, s0); stageWrite(0, s0); }
    __syncthreads();
    if (!isH) {
        f16x8 s1[XCH];
        stageLoad(1, s1);
        xwork(0);
        stageWrite(1, s1);
    }
    __syncthreads();

    for (int t = 0; t < T_STEPS; ++t) {
        if (!isH && t > 0) {
            if (w == 4) publish(t - 1);
            poll(t - 1);
            hTload((t - 1) & 1);
        }
        __syncthreads();   // B1: hT ready
        if (isH) {
            const int p = t & 1;
            f32x4 e0, e1, o0 = {0, 0, 0, 0}, o1 = {0, 0, 0, 0};
#pragma unroll
            for (int jj = 0; jj < 4; ++jj) {
                e0[jj] = xring[p][n][q * 4 + jj];
                e1[jj] = xring[p][n][16 + q * 4 + jj];
            }
            if (t > 0) hseg(e0, o0, e1, o1);
            const f32x4 gv0 = e0 + o0;
            const f32x4 gv1 = e1 + o1;
            float h0v[4], h1v[4];
            act4(gv0, gate, c0, h0v);
            act4(gv1, gate, c1, h1v);
            if (gate == 0) {
#pragma unroll
                for (int jj = 0; jj < 4; ++jj) {
                    hstage[t & 1][q * 4 + jj][hl]      = (f16)h0v[jj];
                    hstage[t & 1][16 + q * 4 + jj][hl] = (f16)h1v[jj];
                }
                if (WLAST && t == T_STEPS - 1) {
#pragma unroll
                    for (int jj = 0; jj < 4; ++jj) {
                        hlast[(bbase + q * 4 + jj) * NHID + jb * 16 + hl]      = h0v[jj];
                        hlast[(bbase + 16 + q * 4 + jj) * NHID + jb * 16 + hl] = h1v[jj];
                    }
                }
            }
        } else {
            f16x8 stg[XCH];
            const bool dost = (t + 2 < T_STEPS);
            if (dost) stageLoad(t + 2, stg);       // issue early (T14)
            if (t + 1 < T_STEPS) xwork(t + 1);     // compute hides the latency
            if (dost) stageWrite(t + 2, stg);      // write late
        }
        __syncthreads();   // B2
    }
    if (w == 4) publish(T_STEPS - 1);   // layer0 needs oseq[T-1]
}

// x [B][T][DIN] f32 -> xp [T][B][DIN] f16 (write-coalesced transpose)
__global__ void pack_x(const float* __restrict__ xin, f16* __restrict__ xp) {
    const int i = blockIdx.x * 256 + threadIdx.x;
    const long long e = (long long)i * 4;
    const int d = (int)(e & (DIN - 1));
    const int b = (int)((e >> 6) & (NBATCH - 1));
    const int t = (int)(e >> 14);
    if (t < T_STEPS) {
        const float4 v = *reinterpret_cast<const float4*>(
            xin + ((size_t)b * T_STEPS + t) * DIN + d);
        f16x4 o;
        o[0] = (f16)v.x; o[1] = (f16)v.y; o[2] = (f16)v.z; o[3] = (f16)v.w;
        *reinterpret_cast<f16x4*>(xp + ((size_t)t * NBATCH + b) * DIN + d) = o;
    }
}

__global__ void fc_kernel(const float* __restrict__ hlast, const float* __restrict__ wfc,
                          const float* __restrict__ bfc, float* __restrict__ out) {
    const int wv = threadIdx.x >> 6, l = threadIdx.x & 63;
    const int b  = blockIdx.x * 4 + wv;
    const float* hr = hlast + b * NHID;
    float s = 0.f;
#pragma unroll
    for (int j = 0; j < 8; ++j) s += hr[l + 64 * j] * wfc[l + 64 * j];
#pragma unroll
    for (int off = 32; off; off >>= 1) s += __shfl_xor(s, off, 64);
    if (l == 0) out[b] = s + bfc[0];
}

extern "C" void kernel_launch(void* const* d_in, const int* in_sizes, int n_in,
                              void* d_out, int out_size, void* d_ws, size_t ws_size,
                              hipStream_t stream) {
    const float* x    = (const float*)d_in[0];
    const float* wih0 = (const float*)d_in[1];
    const float* whh0 = (const float*)d_in[2];
    const float* bih0 = (const float*)d_in[3];
    const float* bhh0 = (const float*)d_in[4];
    const float* wih1 = (const float*)d_in[5];
    const float* whh1 = (const float*)d_in[6];
    const float* bih1 = (const float*)d_in[7];
    const float* bhh1 = (const float*)d_in[8];
    const float* wfc  = (const float*)d_in[9];
    const float* bfc  = (const float*)d_in[10];
    float* out = (float*)d_out;

    char* ws = (char*)d_ws;
    const size_t XPK_ELEMS  = (size_t)NBATCH * T_STEPS * DIN;
    const size_t I1_ELEMS   = (size_t)NBATCH * T_STEPS * NHID;
    const size_t FLAG_ELEMS = (size_t)T_STEPS * NGRP * CBLK;    // 131072
    size_t off = 0;
    f16* xpk = (f16*)(ws + off);        off += XPK_ELEMS * 2;       // [T][B][64]
    f16* i1  = (f16*)(ws + off);        off += I1_ELEMS * 2;        // [T][B][512]
    f16* hb0 = (f16*)(ws + off);        off += (size_t)2 * NBATCH * NHID * 2;
    f16* hb1 = (f16*)(ws + off);        off += (size_t)2 * NBATCH * NHID * 2;
    float* hlast = (float*)(ws + off);  off += (size_t)NBATCH * NHID * 4;
    unsigned* flg0 = (unsigned*)(ws + off); off += FLAG_ELEMS * 4;
    unsigned* flg1 = (unsigned*)(ws + off); off += FLAG_ELEMS * 4;

    // flags must be zero every call (graph replays!)
    hipMemsetAsync(flg0, 0, 2 * FLAG_ELEMS * 4, stream);

    pack_x<<<(int)(XPK_ELEMS / 4 / 256), 256, 0, stream>>>(x, xpk);

    {
        const f16* in0 = xpk;
        f16* oseq0 = i1; float* hl0 = nullptr;
        void* a0[] = { (void*)&in0, (void*)&wih0, (void*)&whh0, (void*)&bih0,
                       (void*)&bhh0, (void*)&hb0, (void*)&oseq0, (void*)&hl0,
                       (void*)&flg0 };
        hipLaunchCooperativeKernel(lstm_layer<DIN, true, false>,
                                   dim3(256), dim3(512), a0, 0, stream);
    }
    {
        const f16* in1 = i1;
        f16* oseq1 = nullptr; float* hl1 = hlast;
        void* a1[] = { (void*)&in1, (void*)&wih1, (void*)&whh1, (void*)&bih1,
                       (void*)&bhh1, (void*)&hb1, (void*)&oseq1, (void*)&hl1,
                       (void*)&flg1 };
        hipLaunchCooperativeKernel(lstm_layer<NHID, false, true>,
                                   dim3(256), dim3(512), a1, 0, stream);
    }

    fc_kernel<<<64, 256, 0, stream>>>(hlast, wfc, bfc, out);
}

// Round 8
// 9246.552 us; speedup vs baseline: 1.4402x; 1.0416x over previous
//
#include <hip/hip_runtime.h>

// 2-layer LSTM (B=256,T=512,D=64,H=512) + FC, fp16 MFMA / fp32 accum.
// Grid 256 coop = 8 batch-groups x 32 hidden-slice blocks, 512 thr, 1 blk/CU.
// v8: LDS bank-conflict fix. Padded rows (stride = KX+8 / NHID+8 f16 -> odd
// granule stride) + phase-aware staging lane map ub=(wr<<3)|(l&7), uc=l>>3 so
// each LDS phase's 8 lanes hit 8 distinct rows/bank-groups. No XOR swizzles.
// Weights in VGPRs; h(t-1) tile staged once/step; time-major input staged
// 2 ahead (T14). Handoff: PROVEN sc1/IF protocol (relaxed agent atomics +
// vmcnt(0) + per-producer flag line + bounded wave-parallel poll).

typedef _Float16 f16;
typedef _Float16 f16x8 __attribute__((ext_vector_type(8)));
typedef _Float16 f16x4 __attribute__((ext_vector_type(4)));
typedef float    f32x4 __attribute__((ext_vector_type(4)));
typedef unsigned long long u64;

#define T_STEPS 512
#define NBATCH  256
#define DIN     64
#define NHID    512
#define NGRP    8
#define CBLK    32
#define NROWS   64   // gate rows per block: 4 gates x 16 hidden
#define HS      (NHID + 8)   // padded hT row stride (f16): 65 granules, odd

__device__ __forceinline__ f32x4 mfma16(f16x8 a, f16x8 b, f32x4 c) {
    return __builtin_amdgcn_mfma_f32_16x16x32_f16(a, b, c, 0, 0, 0);
}

__device__ __forceinline__ f16x8 cvt8(const float* p) {
    const float4 v0 = *reinterpret_cast<const float4*>(p);
    const float4 v1 = *reinterpret_cast<const float4*>(p + 4);
    f16x8 r;
    r[0] = (f16)v0.x; r[1] = (f16)v0.y; r[2] = (f16)v0.z; r[3] = (f16)v0.w;
    r[4] = (f16)v1.x; r[5] = (f16)v1.y; r[6] = (f16)v1.z; r[7] = (f16)v1.w;
    return r;
}

__device__ __forceinline__ void act4(const f32x4 gv, const int gate,
                                     float (&cc)[4], float (&hh)[4])
{
#pragma unroll
    for (int jj = 0; jj < 4; ++jj) {
        const float v  = gv[jj];
        const float xs = (gate == 2) ? 2.0f * v : v;
        const float ee = exp2f(-1.44269504f * xs);
        const float sg = 1.0f / (1.0f + ee);
        const float a  = (gate == 2) ? (2.0f * sg - 1.0f) : sg;   // g uses tanh
        const float a1 = __shfl_xor(a, 1, 64);
        const float a2 = __shfl_xor(a, 2, 64);
        const float a3 = __shfl_xor(a, 3, 64);
        int d;
        float vi, vf, vg, vo;
        d = gate;     vi = d == 0 ? a : d == 1 ? a1 : d == 2 ? a2 : a3;
        d = gate ^ 1; vf = d == 0 ? a : d == 1 ? a1 : d == 2 ? a2 : a3;
        d = gate ^ 2; vg = d == 0 ? a : d == 1 ? a1 : d == 2 ? a2 : a3;
        d = gate ^ 3; vo = d == 0 ? a : d == 1 ? a1 : d == 2 ? a2 : a3;
        const float cn = vf * cc[jj] + vi * vg;
        cc[jj] = cn;
        const float e2 = exp2f(-2.88539008f * cn);   // tanh(c) = 2/(1+e^-2c)-1
        const float th = 2.0f / (1.0f + e2) - 1.0f;
        hh[jj] = vo * th;
    }
}

template<int KX, bool WSEQ, bool WLAST>
__global__ __launch_bounds__(512, 2) void lstm_layer(
    const f16*  __restrict__ in_seq,   // [T][B][KX] fp16, TIME-MAJOR
    const float* __restrict__ w_ih, const float* __restrict__ w_hh,
    const float* __restrict__ b_ih, const float* __restrict__ b_hh,
    f16* __restrict__ hbuf,            // [2][B][NHID] fp16 exchange (parity dbuf)
    f16* __restrict__ oseq,            // [T][B][NHID] fp16 (layer0) or null
    float* __restrict__ hlast,         // [B][NHID] f32 (layer1) or null
    unsigned* flags)                   // [T][NGRP][CBLK] flag lines (pre-zeroed)
{
    constexpr int NKX = KX / 32;       // x-GEMM k-slots
    constexpr int XCH = KX / 64;       // 16B chunks per coop lane per xT row-share
    constexpr int XS  = KX + 8;        // padded xT row stride (f16), odd granules

    __shared__ f16   hT[CBLK * HS];          // padded h(t-1) tile (~33KB)
    __shared__ f16   xT[2][CBLK * XS];       // raw input tiles, 2-deep pipeline
    __shared__ float xring[2][NROWS][33];    // x-projection partials (padded)
    __shared__ f16   hstage[2][CBLK][16];    // h publish staging (parity)
    __shared__ float Lbias[NROWS];

    const int tid = threadIdx.x;
    const int g   = blockIdx.x & 7;
    const int jb  = blockIdx.x >> 3;
    const int bbase = g * CBLK;

    if (tid < NROWS) {
        const int gr = (tid & 3) * NHID + jb * 16 + (tid >> 2);
        Lbias[tid] = b_ih[gr] + b_hh[gr];
    }

    const int w    = tid >> 6;          // wave 0..7
    const bool isH = (w < 4);
    const int wr   = isH ? w : (w - 4);
    const int l    = tid & 63;
    const int col  = l & 15;
    const int q    = l >> 4;
    const int q8   = q << 3;
    const int n    = (wr << 4) | col;   // gate row 0..63
    const int gate = n & 3;
    const int hl   = n >> 2;
    const int grow = (n & 3) * NHID + jb * 16 + (n >> 2);
    // phase-aware staging map: 8 lanes of an LDS phase -> 8 distinct rows
    const int ub   = (wr << 3) | (l & 7);   // batch slot 0..31
    const int uc   = l >> 3;                // chunk group 0..7

    // ---- weights -> registers (one-time): B-frag[s] = W[grow][32s+q8 .. +7]
    f16x8 BW[16];
    if (isH) {
        const float* src = w_hh + (size_t)grow * NHID + q8;
#pragma unroll
        for (int s = 0; s < 16; ++s) BW[s] = cvt8(src + s * 32);
    } else {
        const float* src = w_ih + (size_t)grow * KX + q8;
#pragma unroll
        for (int s = 0; s < NKX; ++s) BW[s] = cvt8(src + s * 32);
    }
    __syncthreads();
    const float bias_n = Lbias[n];

    float c0[4] = {0, 0, 0, 0}, c1[4] = {0, 0, 0, 0};

    // ---- x-tile staging (coop; conflict-free padded writes) ----
    auto stageLoad = [&](int tt, f16x8* stg) {
        const f16* src = in_seq + ((size_t)tt * NBATCH + bbase + ub) * KX;
#pragma unroll
        for (int j = 0; j < XCH; ++j)
            stg[j] = *reinterpret_cast<const f16x8*>(src + (uc * XCH + j) * 8);
    };
    auto stageWrite = [&](int tt, const f16x8* stg) {
        f16* dst = xT[tt & 1] + ub * XS;
#pragma unroll
        for (int j = 0; j < XCH; ++j)
            *reinterpret_cast<f16x8*>(dst + (uc * XCH + j) * 8) = stg[j];
    };

    // ---- h-tile staging: sc1/IF loads -> padded LDS (conflict-free) ----
    auto hTload = [&](int par) {
        const u64* src = reinterpret_cast<const u64*>(
            hbuf + (size_t)par * (NBATCH * NHID) + (size_t)(bbase + ub) * NHID);
        u64 tmp[16];
#pragma unroll
        for (int j = 0; j < 8; ++j) {
            tmp[2*j]   = __hip_atomic_load(src + (uc*8+j)*2,     __ATOMIC_RELAXED, __HIP_MEMORY_SCOPE_AGENT);
            tmp[2*j+1] = __hip_atomic_load(src + (uc*8+j)*2 + 1, __ATOMIC_RELAXED, __HIP_MEMORY_SCOPE_AGENT);
        }
        f16* dst = hT + ub * HS;
#pragma unroll
        for (int j = 0; j < 8; ++j) {
            union { u64 a[2]; f16x8 v; } r;
            r.a[0] = tmp[2*j]; r.a[1] = tmp[2*j+1];
            *reinterpret_cast<f16x8*>(dst + (uc * 8 + j) * 8) = r.v;
        }
    };

    // ---- x-projection of step tt from xT (A:LDS, B:regs) -> xring ----
    auto xwork = [&](int tt) {
        f32x4 e0 = {bias_n, bias_n, bias_n, bias_n}, e1 = e0;
        f32x4 o0 = {0, 0, 0, 0}, o1 = o0;
        const f16* xp = xT[tt & 1];
#pragma unroll
        for (int s = 0; s < NKX; ++s) {
            const f16x8 a0 = *reinterpret_cast<const f16x8*>(xp + col * XS + (q + 4*s) * 8);
            const f16x8 a1 = *reinterpret_cast<const f16x8*>(xp + (col + 16) * XS + (q + 4*s) * 8);
            if (s & 1) { o0 = mfma16(a0, BW[s], o0); o1 = mfma16(a1, BW[s], o1); }
            else       { e0 = mfma16(a0, BW[s], e0); e1 = mfma16(a1, BW[s], e1); }
        }
        const f32x4 s0 = e0 + o0, s1 = e1 + o1;
        const int p = tt & 1;
#pragma unroll
        for (int jj = 0; jj < 4; ++jj) {
            xring[p][n][q * 4 + jj]      = s0[jj];
            xring[p][n][16 + q * 4 + jj] = s1[jj];
        }
    };

    // ---- recurrent GEMM K=512 (A: padded LDS hT, B: regs) ----
    auto hseg = [&](f32x4& e0, f32x4& o0, f32x4& e1, f32x4& o1) {
#pragma unroll
        for (int s = 0; s < 16; ++s) {
            const f16x8 a0 = *reinterpret_cast<const f16x8*>(hT + col * HS + (q + 4*s) * 8);
            const f16x8 a1 = *reinterpret_cast<const f16x8*>(hT + (col + 16) * HS + (q + 4*s) * 8);
            if (s & 1) { o0 = mfma16(a0, BW[s], o0); o1 = mfma16(a1, BW[s], o1); }
            else       { e0 = mfma16(a0, BW[s], e0); e1 = mfma16(a1, BW[s], e1); }
        }
    };

    // ---- wave-4 publish of h(s): sc1 stores -> vmcnt(0) -> flag -> oseq ----
    auto publish = [&](int s) {
        const int b = l >> 1, half = l & 1;
        union { u64 a[2]; f16x8 v; } pk;
        pk.v = *reinterpret_cast<const f16x8*>(&hstage[s & 1][b][half * 8]);
        u64* d64 = reinterpret_cast<u64*>(
            hbuf + (size_t)(s & 1) * (NBATCH * NHID) + (size_t)(bbase + b) * NHID + jb * 16 + half * 8);
        __hip_atomic_store(d64,     pk.a[0], __ATOMIC_RELAXED, __HIP_MEMORY_SCOPE_AGENT);
        __hip_atomic_store(d64 + 1, pk.a[1], __ATOMIC_RELAXED, __HIP_MEMORY_SCOPE_AGENT);
        asm volatile("s_waitcnt vmcnt(0)" ::: "memory");
        if (l == 0)
            __hip_atomic_store(&flags[(size_t)s * (NGRP * CBLK) + g * CBLK + jb], 1u,
                               __ATOMIC_RELAXED, __HIP_MEMORY_SCOPE_AGENT);
        if (WSEQ) {
            f16* od = oseq + ((size_t)s * NBATCH + bbase + b) * NHID + jb * 16 + half * 8;
            *reinterpret_cast<f16x8*>(od) = pk.v;   // plain store, off critical path
        }
    };

    auto poll = [&](int s) {
        const unsigned* fb = flags + (size_t)s * (NGRP * CBLK) + g * CBLK;
        unsigned spins = 0;
        for (;;) {
            unsigned v = 1u;
            if (l < CBLK)
                v = __hip_atomic_load(fb + l, __ATOMIC_RELAXED, __HIP_MEMORY_SCOPE_AGENT);
            if (__all(v != 0)) break;
            __builtin_amdgcn_s_sleep(2);
            if (++spins > (1u << 17)) break;   // fail finite, never hang
        }
        asm volatile("" ::: "memory");
    };

    // ---- prologue: fill xT pipeline + xring[0] ----
    if (!isH) { f16x8 s0[XCH]; stageLoad(0, s0); stageWrite(0, s0); }
    __syncthreads();
    if (!isH) {
        f16x8 s1[XCH];
        stageLoad(1, s1);
        xwork(0);
        stageWrite(1, s1);
    }
    __syncthreads();

    for (int t = 0; t < T_STEPS; ++t) {
        if (!isH && t > 0) {
            if (w == 4) publish(t - 1);
            poll(t - 1);
            hTload((t - 1) & 1);
        }
        __syncthreads();   // B1: hT ready
        if (isH) {
            const int p = t & 1;
            f32x4 e0, e1, o0 = {0, 0, 0, 0}, o1 = {0, 0, 0, 0};
#pragma unroll
            for (int jj = 0; jj < 4; ++jj) {
                e0[jj] = xring[p][n][q * 4 + jj];
                e1[jj] = xring[p][n][16 + q * 4 + jj];
            }
            if (t > 0) hseg(e0, o0, e1, o1);
            const f32x4 gv0 = e0 + o0;
            const f32x4 gv1 = e1 + o1;
            float h0v[4], h1v[4];
            act4(gv0, gate, c0, h0v);
            act4(gv1, gate, c1, h1v);
            if (gate == 0) {
#pragma unroll
                for (int jj = 0; jj < 4; ++jj) {
                    hstage[t & 1][q * 4 + jj][hl]      = (f16)h0v[jj];
                    hstage[t & 1][16 + q * 4 + jj][hl] = (f16)h1v[jj];
                }
                if (WLAST && t == T_STEPS - 1) {
#pragma unroll
                    for (int jj = 0; jj < 4; ++jj) {
                        hlast[(bbase + q * 4 + jj) * NHID + jb * 16 + hl]      = h0v[jj];
                        hlast[(bbase + 16 + q * 4 + jj) * NHID + jb * 16 + hl] = h1v[jj];
                    }
                }
            }
        } else {
            f16x8 stg[XCH];
            const bool dost = (t + 2 < T_STEPS);
            if (dost) stageLoad(t + 2, stg);       // issue early (T14)
            if (t + 1 < T_STEPS) xwork(t + 1);     // compute hides the latency
            if (dost) stageWrite(t + 2, stg);      // write late
        }
        __syncthreads();   // B2
    }
    if (w == 4) publish(T_STEPS - 1);   // layer0 needs oseq[T-1]
}

// x [B][T][DIN] f32 -> xp [T][B][DIN] f16 (write-coalesced transpose)
__global__ void pack_x(const float* __restrict__ xin, f16* __restrict__ xp) {
    const int i = blockIdx.x * 256 + threadIdx.x;
    const long long e = (long long)i * 4;
    const int d = (int)(e & (DIN - 1));
    const int b = (int)((e >> 6) & (NBATCH - 1));
    const int t = (int)(e >> 14);
    if (t < T_STEPS) {
        const float4 v = *reinterpret_cast<const float4*>(
            xin + ((size_t)b * T_STEPS + t) * DIN + d);
        f16x4 o;
        o[0] = (f16)v.x; o[1] = (f16)v.y; o[2] = (f16)v.z; o[3] = (f16)v.w;
        *reinterpret_cast<f16x4*>(xp + ((size_t)t * NBATCH + b) * DIN + d) = o;
    }
}

__global__ void fc_kernel(const float* __restrict__ hlast, const float* __restrict__ wfc,
                          const float* __restrict__ bfc, float* __restrict__ out) {
    const int wv = threadIdx.x >> 6, l = threadIdx.x & 63;
    const int b  = blockIdx.x * 4 + wv;
    const float* hr = hlast + b * NHID;
    float s = 0.f;
#pragma unroll
    for (int j = 0; j < 8; ++j) s += hr[l + 64 * j] * wfc[l + 64 * j];
#pragma unroll
    for (int off = 32; off; off >>= 1) s += __shfl_xor(s, off, 64);
    if (l == 0) out[b] = s + bfc[0];
}

extern "C" void kernel_launch(void* const* d_in, const int* in_sizes, int n_in,
                              void* d_out, int out_size, void* d_ws, size_t ws_size,
                              hipStream_t stream) {
    const float* x    = (const float*)d_in[0];
    const float* wih0 = (const float*)d_in[1];
    const float* whh0 = (const float*)d_in[2];
    const float* bih0 = (const float*)d_in[3];
    const float* bhh0 = (const float*)d_in[4];
    const float* wih1 = (const float*)d_in[5];
    const float* whh1 = (const float*)d_in[6];
    const float* bih1 = (const float*)d_in[7];
    const float* bhh1 = (const float*)d_in[8];
    const float* wfc  = (const float*)d_in[9];
    const float* bfc  = (const float*)d_in[10];
    float* out = (float*)d_out;

    char* ws = (char*)d_ws;
    const size_t XPK_ELEMS  = (size_t)NBATCH * T_STEPS * DIN;
    const size_t I1_ELEMS   = (size_t)NBATCH * T_STEPS * NHID;
    const size_t FLAG_ELEMS = (size_t)T_STEPS * NGRP * CBLK;    // 131072
    size_t off = 0;
    f16* xpk = (f16*)(ws + off);        off += XPK_ELEMS * 2;       // [T][B][64]
    f16* i1  = (f16*)(ws + off);        off += I1_ELEMS * 2;        // [T][B][512]
    f16* hb0 = (f16*)(ws + off);        off += (size_t)2 * NBATCH * NHID * 2;
    f16* hb1 = (f16*)(ws + off);        off += (size_t)2 * NBATCH * NHID * 2;
    float* hlast = (float*)(ws + off);  off += (size_t)NBATCH * NHID * 4;
    unsigned* flg0 = (unsigned*)(ws + off); off += FLAG_ELEMS * 4;
    unsigned* flg1 = (unsigned*)(ws + off); off += FLAG_ELEMS * 4;

    // flags must be zero every call (graph replays!)
    hipMemsetAsync(flg0, 0, 2 * FLAG_ELEMS * 4, stream);

    pack_x<<<(int)(XPK_ELEMS / 4 / 256), 256, 0, stream>>>(x, xpk);

    {
        const f16* in0 = xpk;
        f16* oseq0 = i1; float* hl0 = nullptr;
        void* a0[] = { (void*)&in0, (void*)&wih0, (void*)&whh0, (void*)&bih0,
                       (void*)&bhh0, (void*)&hb0, (void*)&oseq0, (void*)&hl0,
                       (void*)&flg0 };
        hipLaunchCooperativeKernel(lstm_layer<DIN, true, false>,
                                   dim3(256), dim3(512), a0, 0, stream);
    }
    {
        const f16* in1 = i1;
        f16* oseq1 = nullptr; float* hl1 = hlast;
        void* a1[] = { (void*)&in1, (void*)&wih1, (void*)&whh1, (void*)&bih1,
                       (void*)&bhh1, (void*)&hb1, (void*)&oseq1, (void*)&hl1,
                       (void*)&flg1 };
        hipLaunchCooperativeKernel(lstm_layer<NHID, false, true>,
                                   dim3(256), dim3(512), a1, 0, stream);
    }

    fc_kernel<<<64, 256, 0, stream>>>(hlast, wfc, bfc, out);
}

// Round 9
// 8088.138 us; speedup vs baseline: 1.6465x; 1.1432x over previous
//
#include <hip/hip_runtime.h>

// 2-layer LSTM (B=256,T=512,D=64,H=512) + FC, fp16 MFMA / fp32 accum.
// v9: FUSED both layers in one cooperative kernel with 1-step skew.
// Grid 256 = 8 batch-groups x 32 hidden-slices; 512 thr = 2 engines x 4 waves:
//   eng0 (w0-3): layer0 -- publish h0(s-1), poll, stage hT0, GEMM K=64+512, act
//   eng1 (w4-7): layer1 -- publish h1(s-2), poll, stage hT1, GEMM K=512+512, act
// L1's x-input IS the staged hT0 tile (no i1 intermediate, no oseq traffic).
// 513 fused steps instead of 1024 serial steps -> ~2x.
// Handoff: PROVEN sc1/IF protocol (relaxed agent atomics + vmcnt(0) + flag +
// bounded wave-parallel poll). LDS padded rows (R8 conflict fix) throughout.

typedef _Float16 f16;
typedef _Float16 f16x8 __attribute__((ext_vector_type(8)));
typedef _Float16 f16x4 __attribute__((ext_vector_type(4)));
typedef float    f32x4 __attribute__((ext_vector_type(4)));
typedef unsigned long long u64;

#define T_STEPS 512
#define NBATCH  256
#define DIN     64
#define NHID    512
#define NGRP    8
#define CBLK    32
#define NROWS   64          // gate rows per block: 4 gates x 16 hidden
#define HS      (NHID + 8)  // padded hT row stride (f16), odd granule count
#define XS      (DIN + 8)   // padded xT row stride

__device__ __forceinline__ f32x4 mfma16(f16x8 a, f16x8 b, f32x4 c) {
    return __builtin_amdgcn_mfma_f32_16x16x32_f16(a, b, c, 0, 0, 0);
}

__device__ __forceinline__ f16x8 cvt8(const float* p) {
    const float4 v0 = *reinterpret_cast<const float4*>(p);
    const float4 v1 = *reinterpret_cast<const float4*>(p + 4);
    f16x8 r;
    r[0] = (f16)v0.x; r[1] = (f16)v0.y; r[2] = (f16)v0.z; r[3] = (f16)v0.w;
    r[4] = (f16)v1.x; r[5] = (f16)v1.y; r[6] = (f16)v1.z; r[7] = (f16)v1.w;
    return r;
}

__device__ __forceinline__ void act4(const f32x4 gv, const int gate,
                                     float (&cc)[4], float (&hh)[4])
{
#pragma unroll
    for (int jj = 0; jj < 4; ++jj) {
        const float v  = gv[jj];
        const float xs = (gate == 2) ? 2.0f * v : v;
        const float ee = exp2f(-1.44269504f * xs);
        const float sg = 1.0f / (1.0f + ee);
        const float a  = (gate == 2) ? (2.0f * sg - 1.0f) : sg;   // g uses tanh
        const float a1 = __shfl_xor(a, 1, 64);
        const float a2 = __shfl_xor(a, 2, 64);
        const float a3 = __shfl_xor(a, 3, 64);
        int d;
        float vi, vf, vg, vo;
        d = gate;     vi = d == 0 ? a : d == 1 ? a1 : d == 2 ? a2 : a3;
        d = gate ^ 1; vf = d == 0 ? a : d == 1 ? a1 : d == 2 ? a2 : a3;
        d = gate ^ 2; vg = d == 0 ? a : d == 1 ? a1 : d == 2 ? a2 : a3;
        d = gate ^ 3; vo = d == 0 ? a : d == 1 ? a1 : d == 2 ? a2 : a3;
        const float cn = vf * cc[jj] + vi * vg;
        cc[jj] = cn;
        const float e2 = exp2f(-2.88539008f * cn);   // tanh(c) = 2/(1+e^-2c)-1
        const float th = 2.0f / (1.0f + e2) - 1.0f;
        hh[jj] = vo * th;
    }
}

__global__ __launch_bounds__(512, 2) void lstm_fused(
    const f16*  __restrict__ xpk,      // [T][B][DIN] fp16 time-major
    const float* __restrict__ wih0, const float* __restrict__ whh0,
    const float* __restrict__ bih0, const float* __restrict__ bhh0,
    const float* __restrict__ wih1, const float* __restrict__ whh1,
    const float* __restrict__ bih1, const float* __restrict__ bhh1,
    f16* __restrict__ hbuf0,           // [2][B][NHID] layer0 h exchange
    f16* __restrict__ hbuf1,           // [2][B][NHID] layer1 h exchange
    float* __restrict__ hlast,         // [B][NHID] f32 final h1
    unsigned* flags0, unsigned* flags1) // [T][NGRP][CBLK] each, pre-zeroed
{
    __shared__ f16   hT0[CBLK * HS];        // staged h0(s-1) tile (~33KB)
    __shared__ f16   hT1[CBLK * HS];        // staged h1(s-2) tile
    __shared__ f16   xT[3][CBLK * XS];      // input tiles, 3-deep ring
    __shared__ f16   hstage0[2][CBLK][16];  // publish staging, parity
    __shared__ f16   hstage1[2][CBLK][16];
    __shared__ float Lb0[NROWS], Lb1[NROWS];

    const int tid = threadIdx.x;
    const int g   = blockIdx.x & 7;
    const int jb  = blockIdx.x >> 3;
    const int bbase = g * CBLK;

    if (tid < NROWS) {
        const int gr = (tid & 3) * NHID + jb * 16 + (tid >> 2);
        Lb0[tid] = bih0[gr] + bhh0[gr];
        Lb1[tid] = bih1[gr] + bhh1[gr];
    }

    const int w    = tid >> 6;          // wave 0..7
    const int eng  = w >> 2;            // 0: layer0, 1: layer1
    const int wr   = w & 3;
    const int l    = tid & 63;
    const int col  = l & 15;
    const int q    = l >> 4;
    const int q8   = q << 3;
    const int n    = (wr << 4) | col;   // gate row 0..63
    const int gate = n & 3;
    const int hl   = n >> 2;
    const int grow = (n & 3) * NHID + jb * 16 + (n >> 2);
    const int ub   = (wr << 3) | (l & 7);   // staging row (phase-aware, R8)
    const int uc   = l >> 3;                // staging chunk

    // ---- weights -> registers (one-time), f32->f16 ----
    f16x8 BWx[16], BWh[16];
    if (eng == 0) {
        const float* sx = wih0 + (size_t)grow * DIN + q8;
#pragma unroll
        for (int s = 0; s < 2; ++s) BWx[s] = cvt8(sx + s * 32);
        const float* sh = whh0 + (size_t)grow * NHID + q8;
#pragma unroll
        for (int s = 0; s < 16; ++s) BWh[s] = cvt8(sh + s * 32);
    } else {
        const float* sx = wih1 + (size_t)grow * NHID + q8;
#pragma unroll
        for (int s = 0; s < 16; ++s) BWx[s] = cvt8(sx + s * 32);
        const float* sh = whh1 + (size_t)grow * NHID + q8;
#pragma unroll
        for (int s = 0; s < 16; ++s) BWh[s] = cvt8(sh + s * 32);
    }
    __syncthreads();
    const float bias_n = (eng == 0) ? Lb0[n] : Lb1[n];

    float c0[4] = {0,0,0,0}, c1[4] = {0,0,0,0};

    // ---- proven sc1/IF publish: stores -> vmcnt(0) -> flag ----
    auto publish = [&](f16* hb, unsigned* flg, const f16* hsrc, int s) {
        const int b = l >> 1, half = l & 1;
        union { u64 a[2]; f16x8 v; } pk;
        pk.v = *reinterpret_cast<const f16x8*>(hsrc + b * 16 + half * 8);
        u64* d64 = reinterpret_cast<u64*>(
            hb + (size_t)(s & 1) * (NBATCH * NHID) + (size_t)(bbase + b) * NHID + jb * 16 + half * 8);
        __hip_atomic_store(d64,     pk.a[0], __ATOMIC_RELAXED, __HIP_MEMORY_SCOPE_AGENT);
        __hip_atomic_store(d64 + 1, pk.a[1], __ATOMIC_RELAXED, __HIP_MEMORY_SCOPE_AGENT);
        asm volatile("s_waitcnt vmcnt(0)" ::: "memory");
        if (l == 0)
            __hip_atomic_store(flg + (size_t)s * (NGRP * CBLK) + g * CBLK + jb, 1u,
                               __ATOMIC_RELAXED, __HIP_MEMORY_SCOPE_AGENT);
    };

    auto pollf = [&](const unsigned* flg, int s) {
        const unsigned* fb = flg + (size_t)s * (NGRP * CBLK) + g * CBLK;
        unsigned spins = 0;
        for (;;) {
            unsigned v = 1u;
            if (l < CBLK)
                v = __hip_atomic_load(fb + l, __ATOMIC_RELAXED, __HIP_MEMORY_SCOPE_AGENT);
            if (__all(v != 0)) break;
            __builtin_amdgcn_s_sleep(2);
            if (++spins > (1u << 17)) break;   // fail finite, never hang
        }
        asm volatile("" ::: "memory");
    };

    auto hTload = [&](f16* dstT, const f16* hb, int par) {
        const u64* src = reinterpret_cast<const u64*>(
            hb + (size_t)par * (NBATCH * NHID) + (size_t)(bbase + ub) * NHID);
        u64 tmp[16];
#pragma unroll
        for (int j = 0; j < 8; ++j) {
            tmp[2*j]   = __hip_atomic_load(src + (uc*8+j)*2,     __ATOMIC_RELAXED, __HIP_MEMORY_SCOPE_AGENT);
            tmp[2*j+1] = __hip_atomic_load(src + (uc*8+j)*2 + 1, __ATOMIC_RELAXED, __HIP_MEMORY_SCOPE_AGENT);
        }
        f16* dst = dstT + ub * HS;
#pragma unroll
        for (int j = 0; j < 8; ++j) {
            union { u64 a[2]; f16x8 v; } r;
            r.a[0] = tmp[2*j]; r.a[1] = tmp[2*j+1];
            *reinterpret_cast<f16x8*>(dst + (uc * 8 + j) * 8) = r.v;
        }
    };

    // ---- xT prologue: stage steps 0 and 1 into ring slots 0,1 ----
    if (eng == 0) {
#pragma unroll
        for (int t0 = 0; t0 < 2; ++t0) {
            const f16x8 v = *reinterpret_cast<const f16x8*>(
                xpk + ((size_t)t0 * NBATCH + bbase + ub) * DIN + uc * 8);
            *reinterpret_cast<f16x8*>(xT[t0] + ub * XS + uc * 8) = v;
        }
    }
    __syncthreads();

    for (int s = 0; s <= T_STEPS; ++s) {
        // ---- handoff phase: both engines' chains in parallel ----
        if (eng == 0) {
            if (s >= 1) {
                if (w == 0) publish(hbuf0, flags0, &hstage0[(s-1) & 1][0][0], s - 1);
                pollf(flags0, s - 1);
                hTload(hT0, hbuf0, (s - 1) & 1);
            }
        } else {
            if (s >= 2) {
                if (w == 4) publish(hbuf1, flags1, &hstage1[(s-2) & 1][0][0], s - 2);
                pollf(flags1, s - 2);
                hTload(hT1, hbuf1, (s - 2) & 1);
            }
        }
        __syncthreads();   // B1: hT0 (and hT1) staged

        if (eng == 0) {
            if (s < T_STEPS) {
                const bool dost = (s + 2 < T_STEPS);
                f16x8 stg;
                if (dost)   // T14: issue early, write after compute
                    stg = *reinterpret_cast<const f16x8*>(
                        xpk + ((size_t)(s + 2) * NBATCH + bbase + ub) * DIN + uc * 8);
                f32x4 e0 = {bias_n, bias_n, bias_n, bias_n}, e1 = e0;
                f32x4 o0 = {0,0,0,0}, o1 = o0;
                const f16* xp = xT[s % 3];
#pragma unroll
                for (int k = 0; k < 2; ++k) {
                    const f16x8 a0 = *reinterpret_cast<const f16x8*>(xp + col * XS + (q + 4*k) * 8);
                    const f16x8 a1 = *reinterpret_cast<const f16x8*>(xp + (col + 16) * XS + (q + 4*k) * 8);
                    if (k & 1) { o0 = mfma16(a0, BWx[k], o0); o1 = mfma16(a1, BWx[k], o1); }
                    else       { e0 = mfma16(a0, BWx[k], e0); e1 = mfma16(a1, BWx[k], e1); }
                }
                if (s >= 1) {
#pragma unroll
                    for (int k = 0; k < 16; ++k) {
                        const f16x8 a0 = *reinterpret_cast<const f16x8*>(hT0 + col * HS + (q + 4*k) * 8);
                        const f16x8 a1 = *reinterpret_cast<const f16x8*>(hT0 + (col + 16) * HS + (q + 4*k) * 8);
                        if (k & 1) { o0 = mfma16(a0, BWh[k], o0); o1 = mfma16(a1, BWh[k], o1); }
                        else       { e0 = mfma16(a0, BWh[k], e0); e1 = mfma16(a1, BWh[k], e1); }
                    }
                }
                const f32x4 gv0 = e0 + o0, gv1 = e1 + o1;
                float h0v[4], h1v[4];
                act4(gv0, gate, c0, h0v);
                act4(gv1, gate, c1, h1v);
                if (gate == 0) {
#pragma unroll
                    for (int jj = 0; jj < 4; ++jj) {
                        hstage0[s & 1][q * 4 + jj][hl]      = (f16)h0v[jj];
                        hstage0[s & 1][16 + q * 4 + jj][hl] = (f16)h1v[jj];
                    }
                }
                if (dost)
                    *reinterpret_cast<f16x8*>(xT[(s + 2) % 3] + ub * XS + uc * 8) = stg;
            }
        } else {
            if (s >= 1) {   // compute h1(s-1): x-part = Wih1 * h0(s-1) from hT0
                f32x4 e0 = {bias_n, bias_n, bias_n, bias_n}, e1 = e0;
                f32x4 o0 = {0,0,0,0}, o1 = o0;
#pragma unroll
                for (int k = 0; k < 16; ++k) {
                    const f16x8 a0 = *reinterpret_cast<const f16x8*>(hT0 + col * HS + (q + 4*k) * 8);
                    const f16x8 a1 = *reinterpret_cast<const f16x8*>(hT0 + (col + 16) * HS + (q + 4*k) * 8);
                    if (k & 1) { o0 = mfma16(a0, BWx[k], o0); o1 = mfma16(a1, BWx[k], o1); }
                    else       { e0 = mfma16(a0, BWx[k], e0); e1 = mfma16(a1, BWx[k], e1); }
                }
                if (s >= 2) {
#pragma unroll
                    for (int k = 0; k < 16; ++k) {
                        const f16x8 a0 = *reinterpret_cast<const f16x8*>(hT1 + col * HS + (q + 4*k) * 8);
                        const f16x8 a1 = *reinterpret_cast<const f16x8*>(hT1 + (col + 16) * HS + (q + 4*k) * 8);
                        if (k & 1) { o0 = mfma16(a0, BWh[k], o0); o1 = mfma16(a1, BWh[k], o1); }
                        else       { e0 = mfma16(a0, BWh[k], e0); e1 = mfma16(a1, BWh[k], e1); }
                    }
                }
                const f32x4 gv0 = e0 + o0, gv1 = e1 + o1;
                float h0v[4], h1v[4];
                act4(gv0, gate, c0, h0v);
                act4(gv1, gate, c1, h1v);
                if (s == T_STEPS) {
                    if (gate == 0) {
#pragma unroll
                        for (int jj = 0; jj < 4; ++jj) {
                            hlast[(bbase + q * 4 + jj) * NHID + jb * 16 + hl]      = h0v[jj];
                            hlast[(bbase + 16 + q * 4 + jj) * NHID + jb * 16 + hl] = h1v[jj];
                        }
                    }
                } else if (gate == 0) {
#pragma unroll
                    for (int jj = 0; jj < 4; ++jj) {
                        hstage1[(s - 1) & 1][q * 4 + jj][hl]      = (f16)h0v[jj];
                        hstage1[(s - 1) & 1][16 + q * 4 + jj][hl] = (f16)h1v[jj];
                    }
                }
            }
        }
        __syncthreads();   // B2
    }
}

// x [B][T][DIN] f32 -> xp [T][B][DIN] f16 (write-coalesced transpose)
__global__ void pack_x(const float* __restrict__ xin, f16* __restrict__ xp) {
    const int i = blockIdx.x * 256 + threadIdx.x;
    const long long e = (long long)i * 4;
    const int d = (int)(e & (DIN - 1));
    const int b = (int)((e >> 6) & (NBATCH - 1));
    const int t = (int)(e >> 14);
    if (t < T_STEPS) {
        const float4 v = *reinterpret_cast<const float4*>(
            xin + ((size_t)b * T_STEPS + t) * DIN + d);
        f16x4 o;
        o[0] = (f16)v.x; o[1] = (f16)v.y; o[2] = (f16)v.z; o[3] = (f16)v.w;
        *reinterpret_cast<f16x4*>(xp + ((size_t)t * NBATCH + b) * DIN + d) = o;
    }
}

__global__ void fc_kernel(const float* __restrict__ hlast, const float* __restrict__ wfc,
                          const float* __restrict__ bfc, float* __restrict__ out) {
    const int wv = threadIdx.x >> 6, l = threadIdx.x & 63;
    const int b  = blockIdx.x * 4 + wv;
    const float* hr = hlast + b * NHID;
    float s = 0.f;
#pragma unroll
    for (int j = 0; j < 8; ++j) s += hr[l + 64 * j] * wfc[l + 64 * j];
#pragma unroll
    for (int off = 32; off; off >>= 1) s += __shfl_xor(s, off, 64);
    if (l == 0) out[b] = s + bfc[0];
}

extern "C" void kernel_launch(void* const* d_in, const int* in_sizes, int n_in,
                              void* d_out, int out_size, void* d_ws, size_t ws_size,
                              hipStream_t stream) {
    const float* x    = (const float*)d_in[0];
    const float* wih0 = (const float*)d_in[1];
    const float* whh0 = (const float*)d_in[2];
    const float* bih0 = (const float*)d_in[3];
    const float* bhh0 = (const float*)d_in[4];
    const float* wih1 = (const float*)d_in[5];
    const float* whh1 = (const float*)d_in[6];
    const float* bih1 = (const float*)d_in[7];
    const float* bhh1 = (const float*)d_in[8];
    const float* wfc  = (const float*)d_in[9];
    const float* bfc  = (const float*)d_in[10];
    float* out = (float*)d_out;

    char* ws = (char*)d_ws;
    const size_t XPK_ELEMS  = (size_t)NBATCH * T_STEPS * DIN;
    const size_t FLAG_ELEMS = (size_t)T_STEPS * NGRP * CBLK;    // 131072
    size_t off = 0;
    f16* xpk = (f16*)(ws + off);        off += XPK_ELEMS * 2;       // [T][B][64]
    f16* hb0 = (f16*)(ws + off);        off += (size_t)2 * NBATCH * NHID * 2;
    f16* hb1 = (f16*)(ws + off);        off += (size_t)2 * NBATCH * NHID * 2;
    float* hlast = (float*)(ws + off);  off += (size_t)NBATCH * NHID * 4;
    unsigned* flg0 = (unsigned*)(ws + off); off += FLAG_ELEMS * 4;
    unsigned* flg1 = (unsigned*)(ws + off); off += FLAG_ELEMS * 4;

    // flags must be zero every call (graph replays!)
    hipMemsetAsync(flg0, 0, 2 * FLAG_ELEMS * 4, stream);

    pack_x<<<(int)(XPK_ELEMS / 4 / 256), 256, 0, stream>>>(x, xpk);

    {
        const f16* in0 = xpk;
        void* a[] = { (void*)&in0,
                      (void*)&wih0, (void*)&whh0, (void*)&bih0, (void*)&bhh0,
                      (void*)&wih1, (void*)&whh1, (void*)&bih1, (void*)&bhh1,
                      (void*)&hb0, (void*)&hb1, (void*)&hlast,
                      (void*)&flg0, (void*)&flg1 };
        hipLaunchCooperativeKernel(lstm_fused, dim3(256), dim3(512), a, 0, stream);
    }

    fc_kernel<<<64, 256, 0, stream>>>(hlast, wfc, bfc, out);
}

// Round 10
// 7498.519 us; speedup vs baseline: 1.7760x; 1.0786x over previous
//
#include <hip/hip_runtime.h>

// 2-layer LSTM (B=256,T=512,D=64,H=512) + FC, fp16 MFMA / fp32 accum.
// v10 = v9 (fused skewed dual-layer, proven) + hot-line monotonic flag counters.
// Grid 256 = 8 batch-groups x 32 hidden-slices; 512 thr = 2 engines x 4 waves:
//   eng0 (w0-3): layer0 -- publish h0(s-1), poll, stage hT0, GEMM K=64+512, act
//   eng1 (w4-7): layer1 -- publish h1(s-2), poll, stage hT1, GEMM K=512+512, act
// L1's x-input IS the staged hT0 tile (no i1 intermediate).
// Flags: ONE 128B line per producer (g,jb), value = step+1 (monotonic) ->
// lines stay IF-hot (no per-step cold-miss), poll reads spread over 32 lines.
// Handoff protocol otherwise unchanged: relaxed sc1 agent atomics + vmcnt(0)
// before flag + bounded wave-parallel poll. LDS padded rows (R8 fix).

typedef _Float16 f16;
typedef _Float16 f16x8 __attribute__((ext_vector_type(8)));
typedef _Float16 f16x4 __attribute__((ext_vector_type(4)));
typedef float    f32x4 __attribute__((ext_vector_type(4)));
typedef unsigned long long u64;

#define T_STEPS 512
#define NBATCH  256
#define DIN     64
#define NHID    512
#define NGRP    8
#define CBLK    32
#define NROWS   64          // gate rows per block: 4 gates x 16 hidden
#define HS      (NHID + 8)  // padded hT row stride (f16), odd granule count
#define XS      (DIN + 8)   // padded xT row stride
#define FSTRIDE 32          // dwords per flag line (128B)

__device__ __forceinline__ f32x4 mfma16(f16x8 a, f16x8 b, f32x4 c) {
    return __builtin_amdgcn_mfma_f32_16x16x32_f16(a, b, c, 0, 0, 0);
}

__device__ __forceinline__ f16x8 cvt8(const float* p) {
    const float4 v0 = *reinterpret_cast<const float4*>(p);
    const float4 v1 = *reinterpret_cast<const float4*>(p + 4);
    f16x8 r;
    r[0] = (f16)v0.x; r[1] = (f16)v0.y; r[2] = (f16)v0.z; r[3] = (f16)v0.w;
    r[4] = (f16)v1.x; r[5] = (f16)v1.y; r[6] = (f16)v1.z; r[7] = (f16)v1.w;
    return r;
}

__device__ __forceinline__ void act4(const f32x4 gv, const int gate,
                                     float (&cc)[4], float (&hh)[4])
{
#pragma unroll
    for (int jj = 0; jj < 4; ++jj) {
        const float v  = gv[jj];
        const float xs = (gate == 2) ? 2.0f * v : v;
        const float ee = exp2f(-1.44269504f * xs);
        const float sg = 1.0f / (1.0f + ee);
        const float a  = (gate == 2) ? (2.0f * sg - 1.0f) : sg;   // g uses tanh
        const float a1 = __shfl_xor(a, 1, 64);
        const float a2 = __shfl_xor(a, 2, 64);
        const float a3 = __shfl_xor(a, 3, 64);
        int d;
        float vi, vf, vg, vo;
        d = gate;     vi = d == 0 ? a : d == 1 ? a1 : d == 2 ? a2 : a3;
        d = gate ^ 1; vf = d == 0 ? a : d == 1 ? a1 : d == 2 ? a2 : a3;
        d = gate ^ 2; vg = d == 0 ? a : d == 1 ? a1 : d == 2 ? a2 : a3;
        d = gate ^ 3; vo = d == 0 ? a : d == 1 ? a1 : d == 2 ? a2 : a3;
        const float cn = vf * cc[jj] + vi * vg;
        cc[jj] = cn;
        const float e2 = exp2f(-2.88539008f * cn);   // tanh(c) = 2/(1+e^-2c)-1
        const float th = 2.0f / (1.0f + e2) - 1.0f;
        hh[jj] = vo * th;
    }
}

__global__ __launch_bounds__(512, 2) void lstm_fused(
    const f16*  __restrict__ xpk,      // [T][B][DIN] fp16 time-major
    const float* __restrict__ wih0, const float* __restrict__ whh0,
    const float* __restrict__ bih0, const float* __restrict__ bhh0,
    const float* __restrict__ wih1, const float* __restrict__ whh1,
    const float* __restrict__ bih1, const float* __restrict__ bhh1,
    f16* __restrict__ hbuf0,           // [2][B][NHID] layer0 h exchange
    f16* __restrict__ hbuf1,           // [2][B][NHID] layer1 h exchange
    float* __restrict__ hlast,         // [B][NHID] f32 final h1
    unsigned* flags0, unsigned* flags1) // [NGRP*CBLK*FSTRIDE] monotonic counters
{
    __shared__ f16   hT0[CBLK * HS];        // staged h0(s-1) tile (~33KB)
    __shared__ f16   hT1[CBLK * HS];        // staged h1(s-2) tile
    __shared__ f16   xT[3][CBLK * XS];      // input tiles, 3-deep ring
    __shared__ f16   hstage0[2][CBLK][16];  // publish staging, parity
    __shared__ f16   hstage1[2][CBLK][16];
    __shared__ float Lb0[NROWS], Lb1[NROWS];

    const int tid = threadIdx.x;
    const int g   = blockIdx.x & 7;
    const int jb  = blockIdx.x >> 3;
    const int bbase = g * CBLK;

    if (tid < NROWS) {
        const int gr = (tid & 3) * NHID + jb * 16 + (tid >> 2);
        Lb0[tid] = bih0[gr] + bhh0[gr];
        Lb1[tid] = bih1[gr] + bhh1[gr];
    }

    const int w    = tid >> 6;          // wave 0..7
    const int eng  = w >> 2;            // 0: layer0, 1: layer1
    const int wr   = w & 3;
    const int l    = tid & 63;
    const int col  = l & 15;
    const int q    = l >> 4;
    const int q8   = q << 3;
    const int n    = (wr << 4) | col;   // gate row 0..63
    const int gate = n & 3;
    const int hl   = n >> 2;
    const int grow = (n & 3) * NHID + jb * 16 + (n >> 2);
    const int ub   = (wr << 3) | (l & 7);   // staging row (phase-aware, R8)
    const int uc   = l >> 3;                // staging chunk

    // ---- weights -> registers (one-time), f32->f16 ----
    f16x8 BWx[16], BWh[16];
    if (eng == 0) {
        const float* sx = wih0 + (size_t)grow * DIN + q8;
#pragma unroll
        for (int s = 0; s < 2; ++s) BWx[s] = cvt8(sx + s * 32);
        const float* sh = whh0 + (size_t)grow * NHID + q8;
#pragma unroll
        for (int s = 0; s < 16; ++s) BWh[s] = cvt8(sh + s * 32);
    } else {
        const float* sx = wih1 + (size_t)grow * NHID + q8;
#pragma unroll
        for (int s = 0; s < 16; ++s) BWx[s] = cvt8(sx + s * 32);
        const float* sh = whh1 + (size_t)grow * NHID + q8;
#pragma unroll
        for (int s = 0; s < 16; ++s) BWh[s] = cvt8(sh + s * 32);
    }
    __syncthreads();
    const float bias_n = (eng == 0) ? Lb0[n] : Lb1[n];

    float c0[4] = {0,0,0,0}, c1[4] = {0,0,0,0};

    // ---- publish h(sp): sc1 stores -> vmcnt(0) -> flag := sp+1 (own line) ----
    auto publish = [&](f16* hb, unsigned* flg, const f16* hsrc, int sp) {
        const int b = l >> 1, half = l & 1;
        union { u64 a[2]; f16x8 v; } pk;
        pk.v = *reinterpret_cast<const f16x8*>(hsrc + b * 16 + half * 8);
        u64* d64 = reinterpret_cast<u64*>(
            hb + (size_t)(sp & 1) * (NBATCH * NHID) + (size_t)(bbase + b) * NHID + jb * 16 + half * 8);
        __hip_atomic_store(d64,     pk.a[0], __ATOMIC_RELAXED, __HIP_MEMORY_SCOPE_AGENT);
        __hip_atomic_store(d64 + 1, pk.a[1], __ATOMIC_RELAXED, __HIP_MEMORY_SCOPE_AGENT);
        asm volatile("s_waitcnt vmcnt(0)" ::: "memory");
        if (l == 0)
            __hip_atomic_store(flg + (size_t)(g * CBLK + jb) * FSTRIDE,
                               (unsigned)(sp + 1),
                               __ATOMIC_RELAXED, __HIP_MEMORY_SCOPE_AGENT);
    };

    // ---- poll: all 32 producers' counters >= sp+1 (32 distinct hot lines) ----
    auto pollf = [&](const unsigned* flg, int sp) {
        const unsigned target = (unsigned)(sp + 1);
        const unsigned* fp = flg + (size_t)(g * CBLK + (l & 31)) * FSTRIDE;
        unsigned spins = 0;
        for (;;) {
            unsigned v = 0xFFFFFFFFu;
            if (l < CBLK)
                v = __hip_atomic_load(fp, __ATOMIC_RELAXED, __HIP_MEMORY_SCOPE_AGENT);
            if (__all(v >= target)) break;
            __builtin_amdgcn_s_sleep(2);
            if (++spins > (1u << 17)) break;   // fail finite, never hang
        }
        asm volatile("" ::: "memory");
    };

    auto hTload = [&](f16* dstT, const f16* hb, int par) {
        const u64* src = reinterpret_cast<const u64*>(
            hb + (size_t)par * (NBATCH * NHID) + (size_t)(bbase + ub) * NHID);
        u64 tmp[16];
#pragma unroll
        for (int j = 0; j < 8; ++j) {
            tmp[2*j]   = __hip_atomic_load(src + (uc*8+j)*2,     __ATOMIC_RELAXED, __HIP_MEMORY_SCOPE_AGENT);
            tmp[2*j+1] = __hip_atomic_load(src + (uc*8+j)*2 + 1, __ATOMIC_RELAXED, __HIP_MEMORY_SCOPE_AGENT);
        }
        f16* dst = dstT + ub * HS;
#pragma unroll
        for (int j = 0; j < 8; ++j) {
            union { u64 a[2]; f16x8 v; } r;
            r.a[0] = tmp[2*j]; r.a[1] = tmp[2*j+1];
            *reinterpret_cast<f16x8*>(dst + (uc * 8 + j) * 8) = r.v;
        }
    };

    // ---- xT prologue: stage steps 0 and 1 into ring slots 0,1 ----
    if (eng == 0) {
#pragma unroll
        for (int t0 = 0; t0 < 2; ++t0) {
            const f16x8 v = *reinterpret_cast<const f16x8*>(
                xpk + ((size_t)t0 * NBATCH + bbase + ub) * DIN + uc * 8);
            *reinterpret_cast<f16x8*>(xT[t0] + ub * XS + uc * 8) = v;
        }
    }
    __syncthreads();

    for (int s = 0; s <= T_STEPS; ++s) {
        // ---- handoff phase: both engines' chains in parallel ----
        if (eng == 0) {
            if (s >= 1) {
                if (w == 0) publish(hbuf0, flags0, &hstage0[(s-1) & 1][0][0], s - 1);
                pollf(flags0, s - 1);
                hTload(hT0, hbuf0, (s - 1) & 1);
            }
        } else {
            if (s >= 2) {
                if (w == 4) publish(hbuf1, flags1, &hstage1[(s-2) & 1][0][0], s - 2);
                pollf(flags1, s - 2);
                hTload(hT1, hbuf1, (s - 2) & 1);
            }
        }
        __syncthreads();   // B1: hT0 (and hT1) staged

        if (eng == 0) {
            if (s < T_STEPS) {
                const bool dost = (s + 2 < T_STEPS);
                f16x8 stg;
                if (dost)   // T14: issue early, write after compute
                    stg = *reinterpret_cast<const f16x8*>(
                        xpk + ((size_t)(s + 2) * NBATCH + bbase + ub) * DIN + uc * 8);
                f32x4 e0 = {bias_n, bias_n, bias_n, bias_n}, e1 = e0;
                f32x4 o0 = {0,0,0,0}, o1 = o0;
                const f16* xp = xT[s % 3];
#pragma unroll
                for (int k = 0; k < 2; ++k) {
                    const f16x8 a0 = *reinterpret_cast<const f16x8*>(xp + col * XS + (q + 4*k) * 8);
                    const f16x8 a1 = *reinterpret_cast<const f16x8*>(xp + (col + 16) * XS + (q + 4*k) * 8);
                    if (k & 1) { o0 = mfma16(a0, BWx[k], o0); o1 = mfma16(a1, BWx[k], o1); }
                    else       { e0 = mfma16(a0, BWx[k], e0); e1 = mfma16(a1, BWx[k], e1); }
                }
                if (s >= 1) {
#pragma unroll
                    for (int k = 0; k < 16; ++k) {
                        const f16x8 a0 = *reinterpret_cast<const f16x8*>(hT0 + col * HS + (q + 4*k) * 8);
                        const f16x8 a1 = *reinterpret_cast<const f16x8*>(hT0 + (col + 16) * HS + (q + 4*k) * 8);
                        if (k & 1) { o0 = mfma16(a0, BWh[k], o0); o1 = mfma16(a1, BWh[k], o1); }
                        else       { e0 = mfma16(a0, BWh[k], e0); e1 = mfma16(a1, BWh[k], e1); }
                    }
                }
                const f32x4 gv0 = e0 + o0, gv1 = e1 + o1;
                float h0v[4], h1v[4];
                act4(gv0, gate, c0, h0v);
                act4(gv1, gate, c1, h1v);
                if (gate == 0) {
#pragma unroll
                    for (int jj = 0; jj < 4; ++jj) {
                        hstage0[s & 1][q * 4 + jj][hl]      = (f16)h0v[jj];
                        hstage0[s & 1][16 + q * 4 + jj][hl] = (f16)h1v[jj];
                    }
                }
                if (dost)
                    *reinterpret_cast<f16x8*>(xT[(s + 2) % 3] + ub * XS + uc * 8) = stg;
            }
        } else {
            if (s >= 1) {   // compute h1(s-1): x-part = Wih1 * h0(s-1) from hT0
                f32x4 e0 = {bias_n, bias_n, bias_n, bias_n}, e1 = e0;
                f32x4 o0 = {0,0,0,0}, o1 = o0;
#pragma unroll
                for (int k = 0; k < 16; ++k) {
                    const f16x8 a0 = *reinterpret_cast<const f16x8*>(hT0 + col * HS + (q + 4*k) * 8);
                    const f16x8 a1 = *reinterpret_cast<const f16x8*>(hT0 + (col + 16) * HS + (q + 4*k) * 8);
                    if (k & 1) { o0 = mfma16(a0, BWx[k], o0); o1 = mfma16(a1, BWx[k], o1); }
                    else       { e0 = mfma16(a0, BWx[k], e0); e1 = mfma16(a1, BWx[k], e1); }
                }
                if (s >= 2) {
#pragma unroll
                    for (int k = 0; k < 16; ++k) {
                        const f16x8 a0 = *reinterpret_cast<const f16x8*>(hT1 + col * HS + (q + 4*k) * 8);
                        const f16x8 a1 = *reinterpret_cast<const f16x8*>(hT1 + (col + 16) * HS + (q + 4*k) * 8);
                        if (k & 1) { o0 = mfma16(a0, BWh[k], o0); o1 = mfma16(a1, BWh[k], o1); }
                        else       { e0 = mfma16(a0, BWh[k], e0); e1 = mfma16(a1, BWh[k], e1); }
                    }
                }
                const f32x4 gv0 = e0 + o0, gv1 = e1 + o1;
                float h0v[4], h1v[4];
                act4(gv0, gate, c0, h0v);
                act4(gv1, gate, c1, h1v);
                if (s == T_STEPS) {
                    if (gate == 0) {
#pragma unroll
                        for (int jj = 0; jj < 4; ++jj) {
                            hlast[(bbase + q * 4 + jj) * NHID + jb * 16 + hl]      = h0v[jj];
                            hlast[(bbase + 16 + q * 4 + jj) * NHID + jb * 16 + hl] = h1v[jj];
                        }
                    }
                } else if (gate == 0) {
#pragma unroll
                    for (int jj = 0; jj < 4; ++jj) {
                        hstage1[(s - 1) & 1][q * 4 + jj][hl]      = (f16)h0v[jj];
                        hstage1[(s - 1) & 1][16 + q * 4 + jj][hl] = (f16)h1v[jj];
                    }
                }
            }
        }
        __syncthreads();   // B2
    }
}

// x [B][T][DIN] f32 -> xp [T][B][DIN] f16 (write-coalesced transpose)
__global__ void pack_x(const float* __restrict__ xin, f16* __restrict__ xp) {
    const int i = blockIdx.x * 256 + threadIdx.x;
    const long long e = (long long)i * 4;
    const int d = (int)(e & (DIN - 1));
    const int b = (int)((e >> 6) & (NBATCH - 1));
    const int t = (int)(e >> 14);
    if (t < T_STEPS) {
        const float4 v = *reinterpret_cast<const float4*>(
            xin + ((size_t)b * T_STEPS + t) * DIN + d);
        f16x4 o;
        o[0] = (f16)v.x; o[1] = (f16)v.y; o[2] = (f16)v.z; o[3] = (f16)v.w;
        *reinterpret_cast<f16x4*>(xp + ((size_t)t * NBATCH + b) * DIN + d) = o;
    }
}

__global__ void fc_kernel(const float* __restrict__ hlast, const float* __restrict__ wfc,
                          const float* __restrict__ bfc, float* __restrict__ out) {
    const int wv = threadIdx.x >> 6, l = threadIdx.x & 63;
    const int b  = blockIdx.x * 4 + wv;
    const float* hr = hlast + b * NHID;
    float s = 0.f;
#pragma unroll
    for (int j = 0; j < 8; ++j) s += hr[l + 64 * j] * wfc[l + 64 * j];
#pragma unroll
    for (int off = 32; off; off >>= 1) s += __shfl_xor(s, off, 64);
    if (l == 0) out[b] = s + bfc[0];
}

extern "C" void kernel_launch(void* const* d_in, const int* in_sizes, int n_in,
                              void* d_out, int out_size, void* d_ws, size_t ws_size,
                              hipStream_t stream) {
    const float* x    = (const float*)d_in[0];
    const float* wih0 = (const float*)d_in[1];
    const float* whh0 = (const float*)d_in[2];
    const float* bih0 = (const float*)d_in[3];
    const float* bhh0 = (const float*)d_in[4];
    const float* wih1 = (const float*)d_in[5];
    const float* whh1 = (const float*)d_in[6];
    const float* bih1 = (const float*)d_in[7];
    const float* bhh1 = (const float*)d_in[8];
    const float* wfc  = (const float*)d_in[9];
    const float* bfc  = (const float*)d_in[10];
    float* out = (float*)d_out;

    char* ws = (char*)d_ws;
    const size_t XPK_ELEMS  = (size_t)NBATCH * T_STEPS * DIN;
    const size_t FLAG_ELEMS = (size_t)NGRP * CBLK * FSTRIDE;    // 8192 dwords
    size_t off = 0;
    f16* xpk = (f16*)(ws + off);        off += XPK_ELEMS * 2;       // [T][B][64]
    f16* hb0 = (f16*)(ws + off);        off += (size_t)2 * NBATCH * NHID * 2;
    f16* hb1 = (f16*)(ws + off);        off += (size_t)2 * NBATCH * NHID * 2;
    float* hlast = (float*)(ws + off);  off += (size_t)NBATCH * NHID * 4;
    unsigned* flg0 = (unsigned*)(ws + off); off += FLAG_ELEMS * 4;
    unsigned* flg1 = (unsigned*)(ws + off); off += FLAG_ELEMS * 4;

    // flag counters must be zero every call (graph replays!)
    hipMemsetAsync(flg0, 0, 2 * FLAG_ELEMS * 4, stream);

    pack_x<<<(int)(XPK_ELEMS / 4 / 256), 256, 0, stream>>>(x, xpk);

    {
        const f16* in0 = xpk;
        void* a[] = { (void*)&in0,
                      (void*)&wih0, (void*)&whh0, (void*)&bih0, (void*)&bhh0,
                      (void*)&wih1, (void*)&whh1, (void*)&bih1, (void*)&bhh1,
                      (void*)&hb0, (void*)&hb1, (void*)&hlast,
                      (void*)&flg0, (void*)&flg1 };
        hipLaunchCooperativeKernel(lstm_fused, dim3(256), dim3(512), a, 0, stream);
    }

    fc_kernel<<<64, 256, 0, stream>>>(hlast, wfc, bfc, out);
}

// Round 12
// 6760.949 us; speedup vs baseline: 1.9697x; 1.1091x over previous
//
#include <hip/hip_runtime.h>

// 2-layer LSTM (B=256,T=512,D=64,H=512) + FC, fp16 MFMA / fp32 accum.
// v12 = v10 (fused skewed dual-layer, PROVEN sc1/IF protocol) + IN-COMPUTE
// publish: each engine wave publishes its own 4-hid stripe right after act4
// (sc1 stores -> own vmcnt(0) -> LDS counter; 4th wave sets the flag).
// Flag emission no longer waits for B2 / the other engine's GEMM tail, so
// consumer polls typically find flags already set. Handoff = poll+load only.
// L2-local/sc0 path retired permanently (R5 wrong answer, R11 timeout).

typedef _Float16 f16;
typedef _Float16 f16x8 __attribute__((ext_vector_type(8)));
typedef _Float16 f16x4 __attribute__((ext_vector_type(4)));
typedef float    f32x4 __attribute__((ext_vector_type(4)));
typedef unsigned long long u64;

#define T_STEPS 512
#define NBATCH  256
#define DIN     64
#define NHID    512
#define NGRP    8
#define CBLK    32
#define NROWS   64          // gate rows per block: 4 gates x 16 hidden
#define HS      (NHID + 8)  // padded hT row stride (f16), odd granule count
#define XS      (DIN + 8)   // padded xT row stride
#define FSTRIDE 32          // dwords per flag line (128B)

__device__ __forceinline__ f32x4 mfma16(f16x8 a, f16x8 b, f32x4 c) {
    return __builtin_amdgcn_mfma_f32_16x16x32_f16(a, b, c, 0, 0, 0);
}

__device__ __forceinline__ f16x8 cvt8(const float* p) {
    const float4 v0 = *reinterpret_cast<const float4*>(p);
    const float4 v1 = *reinterpret_cast<const float4*>(p + 4);
    f16x8 r;
    r[0] = (f16)v0.x; r[1] = (f16)v0.y; r[2] = (f16)v0.z; r[3] = (f16)v0.w;
    r[4] = (f16)v1.x; r[5] = (f16)v1.y; r[6] = (f16)v1.z; r[7] = (f16)v1.w;
    return r;
}

__device__ __forceinline__ void act4(const f32x4 gv, const int gate,
                                     float (&cc)[4], float (&hh)[4])
{
#pragma unroll
    for (int jj = 0; jj < 4; ++jj) {
        const float v  = gv[jj];
        const float xs = (gate == 2) ? 2.0f * v : v;
        const float ee = exp2f(-1.44269504f * xs);
        const float sg = 1.0f / (1.0f + ee);
        const float a  = (gate == 2) ? (2.0f * sg - 1.0f) : sg;   // g uses tanh
        const float a1 = __shfl_xor(a, 1, 64);
        const float a2 = __shfl_xor(a, 2, 64);
        const float a3 = __shfl_xor(a, 3, 64);
        int d;
        float vi, vf, vg, vo;
        d = gate;     vi = d == 0 ? a : d == 1 ? a1 : d == 2 ? a2 : a3;
        d = gate ^ 1; vf = d == 0 ? a : d == 1 ? a1 : d == 2 ? a2 : a3;
        d = gate ^ 2; vg = d == 0 ? a : d == 1 ? a1 : d == 2 ? a2 : a3;
        d = gate ^ 3; vo = d == 0 ? a : d == 1 ? a1 : d == 2 ? a2 : a3;
        const float cn = vf * cc[jj] + vi * vg;
        cc[jj] = cn;
        const float e2 = exp2f(-2.88539008f * cn);   // tanh(c) = 2/(1+e^-2c)-1
        const float th = 2.0f / (1.0f + e2) - 1.0f;
        hh[jj] = vo * th;
    }
}

__global__ __launch_bounds__(512, 2) void lstm_fused(
    const f16*  __restrict__ xpk,      // [T][B][DIN] fp16 time-major
    const float* __restrict__ wih0, const float* __restrict__ whh0,
    const float* __restrict__ bih0, const float* __restrict__ bhh0,
    const float* __restrict__ wih1, const float* __restrict__ whh1,
    const float* __restrict__ bih1, const float* __restrict__ bhh1,
    f16* __restrict__ hbuf0,           // [2][B][NHID] layer0 h exchange
    f16* __restrict__ hbuf1,           // [2][B][NHID] layer1 h exchange
    float* __restrict__ hlast,         // [B][NHID] f32 final h1
    unsigned* flags0, unsigned* flags1) // [NGRP*CBLK*FSTRIDE] monotonic, memset 0
{
    __shared__ f16   hT0[CBLK * HS];        // staged h0(s-1) tile (~33KB)
    __shared__ f16   hT1[CBLK * HS];        // staged h1(s-2) tile
    __shared__ f16   xT[3][CBLK * XS];      // input tiles, 3-deep ring
    __shared__ f16   hstage0[2][CBLK][16];  // publish staging, parity
    __shared__ f16   hstage1[2][CBLK][16];
    __shared__ float Lb0[NROWS], Lb1[NROWS];
    __shared__ unsigned pubcnt[2][2];       // [engine][parity] wave-arrival count

    const int tid = threadIdx.x;
    const int g   = blockIdx.x & 7;
    const int jb  = blockIdx.x >> 3;
    const int bbase = g * CBLK;

    if (tid == 0) {
        pubcnt[0][0] = 0; pubcnt[0][1] = 0;
        pubcnt[1][0] = 0; pubcnt[1][1] = 0;
    }
    if (tid < NROWS) {
        const int gr = (tid & 3) * NHID + jb * 16 + (tid >> 2);
        Lb0[tid] = bih0[gr] + bhh0[gr];
        Lb1[tid] = bih1[gr] + bhh1[gr];
    }

    const int w    = tid >> 6;          // wave 0..7
    const int eng  = w >> 2;            // 0: layer0, 1: layer1
    const int wr   = w & 3;
    const int l    = tid & 63;
    const int col  = l & 15;
    const int q    = l >> 4;
    const int q8   = q << 3;
    const int n    = (wr << 4) | col;   // gate row 0..63
    const int gate = n & 3;
    const int hl   = n >> 2;
    const int grow = (n & 3) * NHID + jb * 16 + (n >> 2);
    const int ub   = (wr << 3) | (l & 7);   // staging row (phase-aware, R8)
    const int uc   = l >> 3;                // staging chunk

    // ---- weights -> registers (one-time), f32->f16 ----
    f16x8 BWx[16], BWh[16];
    if (eng == 0) {
        const float* sx = wih0 + (size_t)grow * DIN + q8;
#pragma unroll
        for (int s = 0; s < 2; ++s) BWx[s] = cvt8(sx + s * 32);
        const float* sh = whh0 + (size_t)grow * NHID + q8;
#pragma unroll
        for (int s = 0; s < 16; ++s) BWh[s] = cvt8(sh + s * 32);
    } else {
        const float* sx = wih1 + (size_t)grow * NHID + q8;
#pragma unroll
        for (int s = 0; s < 16; ++s) BWx[s] = cvt8(sx + s * 32);
        const float* sh = whh1 + (size_t)grow * NHID + q8;
#pragma unroll
        for (int s = 0; s < 16; ++s) BWh[s] = cvt8(sh + s * 32);
    }
    __syncthreads();
    const float bias_n = (eng == 0) ? Lb0[n] : Lb1[n];

    float c0[4] = {0,0,0,0}, c1[4] = {0,0,0,0};

    // ---- in-compute per-wave stripe publish of h(sp) ----
    // stripe = this wave's 4 hid cols [wr*4..wr*4+3] x 32 batches, read from
    // hstage (written by this wave's gate==0 lanes). sc1 stores -> own
    // vmcnt(0) -> LDS counter; 4th arriving wave writes flag = sp+1.
    auto pubwave = [&](f16* hb, unsigned* flg, const f16* hsbase, int sp, int ci) {
        asm volatile("s_waitcnt lgkmcnt(0)" ::: "memory");  // hstage writes visible
        if (l < CBLK) {
            const u64 v8 = *reinterpret_cast<const u64*>(hsbase + l * 16 + wr * 4);
            u64* dst = reinterpret_cast<u64*>(
                hb + (size_t)(sp & 1) * (NBATCH * NHID)
                   + (size_t)(bbase + l) * NHID + jb * 16 + wr * 4);
            __hip_atomic_store(dst, v8, __ATOMIC_RELAXED, __HIP_MEMORY_SCOPE_AGENT);
        }
        asm volatile("s_waitcnt vmcnt(0)" ::: "memory");    // own stores drained
        if (l == 0) {
            const unsigned old = atomicAdd(&pubcnt[ci][sp & 1], 1u);
            if (old == 3u) {
                pubcnt[ci][sp & 1] = 0u;   // safe: barriers separate next reuse
                __hip_atomic_store(flg + (size_t)(g * CBLK + jb) * FSTRIDE,
                                   (unsigned)(sp + 1),
                                   __ATOMIC_RELAXED, __HIP_MEMORY_SCOPE_AGENT);
            }
        }
    };

    // ---- poll all 32 producers: counter >= sp+1 (hot lines) ----
    auto pollf = [&](const unsigned* flg, int sp) {
        const unsigned target = (unsigned)(sp + 1);
        const unsigned* fp = flg + (size_t)(g * CBLK + (l & 31)) * FSTRIDE;
        unsigned spins = 0;
        for (;;) {
            unsigned v = 0xFFFFFFFFu;
            if (l < CBLK)
                v = __hip_atomic_load(fp, __ATOMIC_RELAXED, __HIP_MEMORY_SCOPE_AGENT);
            if (__all(v >= target)) break;
            __builtin_amdgcn_s_sleep(2);
            if (++spins > (1u << 17)) break;   // fail finite, never hang
        }
        asm volatile("" ::: "memory");
    };

    auto hTload = [&](f16* dstT, const f16* hb, int par) {
        const u64* src = reinterpret_cast<const u64*>(
            hb + (size_t)par * (NBATCH * NHID) + (size_t)(bbase + ub) * NHID);
        u64 tmp[16];
#pragma unroll
        for (int j = 0; j < 8; ++j) {
            tmp[2*j]   = __hip_atomic_load(src + (uc*8+j)*2,     __ATOMIC_RELAXED, __HIP_MEMORY_SCOPE_AGENT);
            tmp[2*j+1] = __hip_atomic_load(src + (uc*8+j)*2 + 1, __ATOMIC_RELAXED, __HIP_MEMORY_SCOPE_AGENT);
        }
        f16* dst = dstT + ub * HS;
#pragma unroll
        for (int j = 0; j < 8; ++j) {
            union { u64 a[2]; f16x8 v; } r;
            r.a[0] = tmp[2*j]; r.a[1] = tmp[2*j+1];
            *reinterpret_cast<f16x8*>(dst + (uc * 8 + j) * 8) = r.v;
        }
    };

    // ---- xT prologue: stage steps 0 and 1 into ring slots 0,1 ----
    if (eng == 0) {
#pragma unroll
        for (int t0 = 0; t0 < 2; ++t0) {
            const f16x8 v = *reinterpret_cast<const f16x8*>(
                xpk + ((size_t)t0 * NBATCH + bbase + ub) * DIN + uc * 8);
            *reinterpret_cast<f16x8*>(xT[t0] + ub * XS + uc * 8) = v;
        }
    }
    __syncthreads();

    for (int s = 0; s <= T_STEPS; ++s) {
        // ---- handoff: poll + tile-load only (flags emitted in-compute) ----
        if (eng == 0) {
            if (s >= 1) {
                pollf(flags0, s - 1);
                hTload(hT0, hbuf0, (s - 1) & 1);
            }
        } else {
            if (s >= 2) {
                pollf(flags1, s - 2);
                hTload(hT1, hbuf1, (s - 2) & 1);
            }
        }
        __syncthreads();   // B1: hT0 (and hT1) staged

        if (eng == 0) {
            if (s < T_STEPS) {
                const bool dost = (s + 2 < T_STEPS);
                f16x8 stg;
                if (dost)   // T14: issue early, write after compute
                    stg = *reinterpret_cast<const f16x8*>(
                        xpk + ((size_t)(s + 2) * NBATCH + bbase + ub) * DIN + uc * 8);
                f32x4 e0 = {bias_n, bias_n, bias_n, bias_n}, e1 = e0;
                f32x4 o0 = {0,0,0,0}, o1 = o0;
                const f16* xp = xT[s % 3];
#pragma unroll
                for (int k = 0; k < 2; ++k) {
                    const f16x8 a0 = *reinterpret_cast<const f16x8*>(xp + col * XS + (q + 4*k) * 8);
                    const f16x8 a1 = *reinterpret_cast<const f16x8*>(xp + (col + 16) * XS + (q + 4*k) * 8);
                    if (k & 1) { o0 = mfma16(a0, BWx[k], o0); o1 = mfma16(a1, BWx[k], o1); }
                    else       { e0 = mfma16(a0, BWx[k], e0); e1 = mfma16(a1, BWx[k], e1); }
                }
                if (s >= 1) {
#pragma unroll
                    for (int k = 0; k < 16; ++k) {
                        const f16x8 a0 = *reinterpret_cast<const f16x8*>(hT0 + col * HS + (q + 4*k) * 8);
                        const f16x8 a1 = *reinterpret_cast<const f16x8*>(hT0 + (col + 16) * HS + (q + 4*k) * 8);
                        if (k & 1) { o0 = mfma16(a0, BWh[k], o0); o1 = mfma16(a1, BWh[k], o1); }
                        else       { e0 = mfma16(a0, BWh[k], e0); e1 = mfma16(a1, BWh[k], e1); }
                    }
                }
                const f32x4 gv0 = e0 + o0, gv1 = e1 + o1;
                float h0v[4], h1v[4];
                act4(gv0, gate, c0, h0v);
                act4(gv1, gate, c1, h1v);
                if (gate == 0) {
#pragma unroll
                    for (int jj = 0; jj < 4; ++jj) {
                        hstage0[s & 1][q * 4 + jj][hl]      = (f16)h0v[jj];
                        hstage0[s & 1][16 + q * 4 + jj][hl] = (f16)h1v[jj];
                    }
                }
                // publish h0(s) NOW (flag0 := s+1 when all 4 waves drained)
                pubwave(hbuf0, flags0, &hstage0[s & 1][0][0], s, 0);
                if (dost)
                    *reinterpret_cast<f16x8*>(xT[(s + 2) % 3] + ub * XS + uc * 8) = stg;
            }
        } else {
            if (s >= 1) {   // compute h1(s-1): x-part = Wih1 * h0(s-1) from hT0
                f32x4 e0 = {bias_n, bias_n, bias_n, bias_n}, e1 = e0;
                f32x4 o0 = {0,0,0,0}, o1 = o0;
#pragma unroll
                for (int k = 0; k < 16; ++k) {
                    const f16x8 a0 = *reinterpret_cast<const f16x8*>(hT0 + col * HS + (q + 4*k) * 8);
                    const f16x8 a1 = *reinterpret_cast<const f16x8*>(hT0 + (col + 16) * HS + (q + 4*k) * 8);
                    if (k & 1) { o0 = mfma16(a0, BWx[k], o0); o1 = mfma16(a1, BWx[k], o1); }
                    else       { e0 = mfma16(a0, BWx[k], e0); e1 = mfma16(a1, BWx[k], e1); }
                }
                if (s >= 2) {
#pragma unroll
                    for (int k = 0; k < 16; ++k) {
                        const f16x8 a0 = *reinterpret_cast<const f16x8*>(hT1 + col * HS + (q + 4*k) * 8);
                        const f16x8 a1 = *reinterpret_cast<const f16x8*>(hT1 + (col + 16) * HS + (q + 4*k) * 8);
                        if (k & 1) { o0 = mfma16(a0, BWh[k], o0); o1 = mfma16(a1, BWh[k], o1); }
                        else       { e0 = mfma16(a0, BWh[k], e0); e1 = mfma16(a1, BWh[k], e1); }
                    }
                }
                const f32x4 gv0 = e0 + o0, gv1 = e1 + o1;
                float h0v[4], h1v[4];
                act4(gv0, gate, c0, h0v);
                act4(gv1, gate, c1, h1v);
                if (s == T_STEPS) {
                    if (gate == 0) {
#pragma unroll
                        for (int jj = 0; jj < 4; ++jj) {
                            hlast[(bbase + q * 4 + jj) * NHID + jb * 16 + hl]      = h0v[jj];
                            hlast[(bbase + 16 + q * 4 + jj) * NHID + jb * 16 + hl] = h1v[jj];
                        }
                    }
                } else {
                    if (gate == 0) {
#pragma unroll
                        for (int jj = 0; jj < 4; ++jj) {
                            hstage1[(s - 1) & 1][q * 4 + jj][hl]      = (f16)h0v[jj];
                            hstage1[(s - 1) & 1][16 + q * 4 + jj][hl] = (f16)h1v[jj];
                        }
                    }
                    // publish h1(s-1) NOW (flag1 := s when all 4 waves drained)
                    pubwave(hbuf1, flags1, &hstage1[(s - 1) & 1][0][0], s - 1, 1);
                }
            }
        }
        __syncthreads();   // B2
    }
}

// x [B][T][DIN] f32 -> xp [T][B][DIN] f16 (write-coalesced transpose)
__global__ void pack_x(const float* __restrict__ xin, f16* __restrict__ xp) {
    const int i = blockIdx.x * 256 + threadIdx.x;
    const long long e = (long long)i * 4;
    const int d = (int)(e & (DIN - 1));
    const int b = (int)((e >> 6) & (NBATCH - 1));
    const int t = (int)(e >> 14);
    if (t < T_STEPS) {
        const float4 v = *reinterpret_cast<const float4*>(
            xin + ((size_t)b * T_STEPS + t) * DIN + d);
        f16x4 o;
        o[0] = (f16)v.x; o[1] = (f16)v.y; o[2] = (f16)v.z; o[3] = (f16)v.w;
        *reinterpret_cast<f16x4*>(xp + ((size_t)t * NBATCH + b) * DIN + d) = o;
    }
}

__global__ void fc_kernel(const float* __restrict__ hlast, const float* __restrict__ wfc,
                          const float* __restrict__ bfc, float* __restrict__ out) {
    const int wv = threadIdx.x >> 6, l = threadIdx.x & 63;
    const int b  = blockIdx.x * 4 + wv;
    const float* hr = hlast + b * NHID;
    float s = 0.f;
#pragma unroll
    for (int j = 0; j < 8; ++j) s += hr[l + 64 * j] * wfc[l + 64 * j];
#pragma unroll
    for (int off = 32; off; off >>= 1) s += __shfl_xor(s, off, 64);
    if (l == 0) out[b] = s + bfc[0];
}

extern "C" void kernel_launch(void* const* d_in, const int* in_sizes, int n_in,
                              void* d_out, int out_size, void* d_ws, size_t ws_size,
                              hipStream_t stream) {
    const float* x    = (const float*)d_in[0];
    const float* wih0 = (const float*)d_in[1];
    const float* whh0 = (const float*)d_in[2];
    const float* bih0 = (const float*)d_in[3];
    const float* bhh0 = (const float*)d_in[4];
    const float* wih1 = (const float*)d_in[5];
    const float* whh1 = (const float*)d_in[6];
    const float* bih1 = (const float*)d_in[7];
    const float* bhh1 = (const float*)d_in[8];
    const float* wfc  = (const float*)d_in[9];
    const float* bfc  = (const float*)d_in[10];
    float* out = (float*)d_out;

    char* ws = (char*)d_ws;
    const size_t XPK_ELEMS  = (size_t)NBATCH * T_STEPS * DIN;
    const size_t FLAG_ELEMS = (size_t)NGRP * CBLK * FSTRIDE;    // 8192 dwords
    size_t off = 0;
    f16* xpk = (f16*)(ws + off);        off += XPK_ELEMS * 2;
    f16* hb0 = (f16*)(ws + off);        off += (size_t)2 * NBATCH * NHID * 2;
    f16* hb1 = (f16*)(ws + off);        off += (size_t)2 * NBATCH * NHID * 2;
    float* hlast = (float*)(ws + off);  off += (size_t)NBATCH * NHID * 4;
    unsigned* flg0 = (unsigned*)(ws + off); off += FLAG_ELEMS * 4;
    unsigned* flg1 = (unsigned*)(ws + off); off += FLAG_ELEMS * 4;

    // flag counters must be zero every call (graph replays!)
    hipMemsetAsync(flg0, 0, 2 * FLAG_ELEMS * 4, stream);

    pack_x<<<(int)(XPK_ELEMS / 4 / 256), 256, 0, stream>>>(x, xpk);

    {
        const f16* in0 = xpk;
        void* a[] = { (void*)&in0,
                      (void*)&wih0, (void*)&whh0, (void*)&bih0, (void*)&bhh0,
                      (void*)&wih1, (void*)&whh1, (void*)&bih1, (void*)&bhh1,
                      (void*)&hb0, (void*)&hb1, (void*)&hlast,
                      (void*)&flg0, (void*)&flg1 };
        hipLaunchCooperativeKernel(lstm_fused, dim3(256), dim3(512), a, 0, stream);
    }

    fc_kernel<<<64, 256, 0, stream>>>(hlast, wfc, bfc, out);
}

// Round 14
// 4903.999 us; speedup vs baseline: 2.7156x; 1.3787x over previous
//
#include <hip/hip_runtime.h>

// 2-layer LSTM (B=256,T=512,D=64,H=512) + FC, fp16 MFMA / fp32 accum.
// v13b: TWO independent batch-group chains per block (16 groups x 16 batches).
// Block (pid=blockIdx&7, jb=blockIdx>>3) serves groups gA=2pid, gB=2pid+1 with
// SHARED weight registers. Per iteration: handoff A -> issue B loads ->
// GEMM A (hides B-load latency) -> publish A -> stage B -> GEMM B -> publish B.
// Exchange protocol per chain = PROVEN sc1/IF relaxed atomics + vmcnt(0) +
// monotonic hot-line flags + bounded poll (R10/R12). Pods are closed (32
// blocks serve exactly their 2 groups) -> same lockstep topology as before.
// (v13 fix: act4 takes float* instead of float(&)[4].)

typedef _Float16 f16;
typedef _Float16 f16x8 __attribute__((ext_vector_type(8)));
typedef _Float16 f16x4 __attribute__((ext_vector_type(4)));
typedef float    f32x4 __attribute__((ext_vector_type(4)));
typedef unsigned long long u64;

#define T_STEPS 512
#define NBATCH  256
#define DIN     64
#define NHID    512
#define GB      16          // batches per group
#define CBLK    32          // blocks (hid slices) per group
#define NGRP2   16          // number of groups
#define NROWS   64          // gate rows per block: 4 gates x 16 hidden
#define HS      (NHID + 8)  // padded tile row stride (f16)
#define XS      (DIN + 8)
#define FSTRIDE 32          // dwords per flag line (128B)

__device__ __forceinline__ f32x4 mfma16(f16x8 a, f16x8 b, f32x4 c) {
    return __builtin_amdgcn_mfma_f32_16x16x32_f16(a, b, c, 0, 0, 0);
}

__device__ __forceinline__ f16x8 cvt8(const float* p) {
    const float4 v0 = *reinterpret_cast<const float4*>(p);
    const float4 v1 = *reinterpret_cast<const float4*>(p + 4);
    f16x8 r;
    r[0] = (f16)v0.x; r[1] = (f16)v0.y; r[2] = (f16)v0.z; r[3] = (f16)v0.w;
    r[4] = (f16)v1.x; r[5] = (f16)v1.y; r[6] = (f16)v1.z; r[7] = (f16)v1.w;
    return r;
}

__device__ __forceinline__ void act4(const f32x4 gv, const int gate,
                                     float* cc, float* hh)
{
#pragma unroll
    for (int jj = 0; jj < 4; ++jj) {
        const float v  = gv[jj];
        const float xs = (gate == 2) ? 2.0f * v : v;
        const float ee = exp2f(-1.44269504f * xs);
        const float sg = 1.0f / (1.0f + ee);
        const float a  = (gate == 2) ? (2.0f * sg - 1.0f) : sg;   // g uses tanh
        const float a1 = __shfl_xor(a, 1, 64);
        const float a2 = __shfl_xor(a, 2, 64);
        const float a3 = __shfl_xor(a, 3, 64);
        int d;
        float vi, vf, vg, vo;
        d = gate;     vi = d == 0 ? a : d == 1 ? a1 : d == 2 ? a2 : a3;
        d = gate ^ 1; vf = d == 0 ? a : d == 1 ? a1 : d == 2 ? a2 : a3;
        d = gate ^ 2; vg = d == 0 ? a : d == 1 ? a1 : d == 2 ? a2 : a3;
        d = gate ^ 3; vo = d == 0 ? a : d == 1 ? a1 : d == 2 ? a2 : a3;
        const float cn = vf * cc[jj] + vi * vg;
        cc[jj] = cn;
        const float e2 = exp2f(-2.88539008f * cn);   // tanh(c) = 2/(1+e^-2c)-1
        const float th = 2.0f / (1.0f + e2) - 1.0f;
        hh[jj] = vo * th;
    }
}

__global__ __launch_bounds__(512, 2) void lstm_fused(
    const f16*  __restrict__ xpk,      // [T][B][DIN] fp16 time-major
    const float* __restrict__ wih0, const float* __restrict__ whh0,
    const float* __restrict__ bih0, const float* __restrict__ bhh0,
    const float* __restrict__ wih1, const float* __restrict__ whh1,
    const float* __restrict__ bih1, const float* __restrict__ bhh1,
    f16* __restrict__ hbuf0,           // [2][B][NHID] layer0 h exchange
    f16* __restrict__ hbuf1,           // [2][B][NHID] layer1 h exchange
    float* __restrict__ hlast,         // [B][NHID] f32 final h1
    unsigned* flags0, unsigned* flags1) // [NGRP2*CBLK*FSTRIDE] monotonic, memset 0
{
    __shared__ f16 hT0A[GB * HS], hT0B[GB * HS];   // h0 tiles, chains A/B
    __shared__ f16 hT1A[GB * HS], hT1B[GB * HS];   // h1 tiles
    __shared__ f16 xTile[2][3][GB * XS];           // x tiles [chain][slot]
    __shared__ f16 hs0[2][2][GB * 16];             // publish stage [chain][par]
    __shared__ f16 hs1[2][2][GB * 16];
    __shared__ float Lb0[NROWS], Lb1[NROWS];
    __shared__ unsigned pubcnt[2][2][2];           // [eng][chain][par]

    const int tid = threadIdx.x;
    const int pid = blockIdx.x & 7;
    const int jb  = blockIdx.x >> 3;
    const int gA  = pid * 2, gB_ = pid * 2 + 1;
    const int bbA = gA * GB, bbB = gB_ * GB;

    if (tid < 8) reinterpret_cast<unsigned*>(pubcnt)[tid] = 0u;
    if (tid < NROWS) {
        const int gr = (tid & 3) * NHID + jb * 16 + (tid >> 2);
        Lb0[tid] = bih0[gr] + bhh0[gr];
        Lb1[tid] = bih1[gr] + bhh1[gr];
    }

    const int w    = tid >> 6;          // wave 0..7
    const int eng  = w >> 2;            // 0: layer0, 1: layer1
    const int wr   = w & 3;
    const int l    = tid & 63;
    const int col  = l & 15;
    const int q    = l >> 4;
    const int q8   = q << 3;
    const int n    = (wr << 4) | col;   // gate row 0..63
    const int gate = n & 3;
    const int hl   = n >> 2;
    const int grow = (n & 3) * NHID + jb * 16 + (n >> 2);
    const int rb   = (wr << 2) | (l & 3);   // staging row 0..15
    const int rc   = l >> 2;                // staging chunk 0..15

    // ---- weights -> registers (one-time), f32->f16; SHARED by both chains ----
    f16x8 BWx[16], BWh[16];
    if (eng == 0) {
        const float* sx = wih0 + (size_t)grow * DIN + q8;
#pragma unroll
        for (int s = 0; s < 2; ++s) BWx[s] = cvt8(sx + s * 32);
        const float* sh = whh0 + (size_t)grow * NHID + q8;
#pragma unroll
        for (int s = 0; s < 16; ++s) BWh[s] = cvt8(sh + s * 32);
    } else {
        const float* sx = wih1 + (size_t)grow * NHID + q8;
#pragma unroll
        for (int s = 0; s < 16; ++s) BWx[s] = cvt8(sx + s * 32);
        const float* sh = whh1 + (size_t)grow * NHID + q8;
#pragma unroll
        for (int s = 0; s < 16; ++s) BWh[s] = cvt8(sh + s * 32);
    }
    __syncthreads();
    const float bias_n = (eng == 0) ? Lb0[n] : Lb1[n];

    float cA[4] = {0,0,0,0}, cB[4] = {0,0,0,0};   // cell state per chain

    // ---- bounded wave-parallel poll of a group's 32 producer counters ----
    auto pollf = [&](const unsigned* flg, int grp, int sp) {
        const unsigned target = (unsigned)(sp + 1);
        const unsigned* fp = flg + (size_t)(grp * CBLK + (l & 31)) * FSTRIDE;
        unsigned spins = 0;
        for (;;) {
            unsigned v = 0xFFFFFFFFu;
            if (l < CBLK)
                v = __hip_atomic_load(fp, __ATOMIC_RELAXED, __HIP_MEMORY_SCOPE_AGENT);
            if (__all(v >= target)) break;
            __builtin_amdgcn_s_sleep(2);
            if (++spins > (1u << 15)) break;   // fail finite, never hang
        }
        asm volatile("" ::: "memory");
    };

    // issue 8x8B sc1 loads of one 16x512 h tile slice (use deferred by compiler)
    auto ldissue = [&](u64* r, const f16* hb, int par, int bb) {
        const u64* src = reinterpret_cast<const u64*>(
            hb + (size_t)par * (NBATCH * NHID) + (size_t)(bb + rb) * NHID) + rc * 8;
#pragma unroll
        for (int j = 0; j < 8; ++j)
            r[j] = __hip_atomic_load(src + j, __ATOMIC_RELAXED, __HIP_MEMORY_SCOPE_AGENT);
    };
    auto tilewr = [&](f16* t, const u64* r) {
        f16* dst = t + rb * HS + rc * 32;
#pragma unroll
        for (int j = 0; j < 8; ++j)
            *reinterpret_cast<u64*>(dst + j * 4) = r[j];
    };

    // in-compute per-wave stripe publish (R12): sc1 stores -> own vmcnt(0) ->
    // LDS counter; 4th wave writes flag = sp+1.
    auto pubwave = [&](f16* hb, unsigned* flg, int grp, int bb, const f16* hsrc,
                       int sp, int eci, int cci) {
        asm volatile("s_waitcnt lgkmcnt(0)" ::: "memory");
        if (l < GB) {
            const u64 v8 = *reinterpret_cast<const u64*>(hsrc + l * 16 + wr * 4);
            u64* dst = reinterpret_cast<u64*>(
                hb + (size_t)(sp & 1) * (NBATCH * NHID)
                   + (size_t)(bb + l) * NHID + jb * 16 + wr * 4);
            __hip_atomic_store(dst, v8, __ATOMIC_RELAXED, __HIP_MEMORY_SCOPE_AGENT);
        }
        asm volatile("s_waitcnt vmcnt(0)" ::: "memory");
        if (l == 0) {
            const unsigned old = atomicAdd(&pubcnt[eci][cci][sp & 1], 1u);
            if (old == 3u) {
                pubcnt[eci][cci][sp & 1] = 0u;
                __hip_atomic_store(flg + (size_t)(grp * CBLK + jb) * FSTRIDE,
                                   (unsigned)(sp + 1),
                                   __ATOMIC_RELAXED, __HIP_MEMORY_SCOPE_AGENT);
            }
        }
    };

    // ---- eng0 step for one chain: K=64 x-GEMM + K=512 h-GEMM, act, publish ----
    auto comp0 = [&](const f16* xp, const f16* t0, float* cc, f16* hst,
                     int grp, int bb, int s_, bool doh, int cci) {
        f32x4 e0 = {bias_n, bias_n, bias_n, bias_n};
        f32x4 o0 = {0,0,0,0};
#pragma unroll
        for (int k = 0; k < 2; ++k) {
            const f16x8 a0 = *reinterpret_cast<const f16x8*>(xp + col * XS + (q + 4*k) * 8);
            if (k & 1) o0 = mfma16(a0, BWx[k], o0); else e0 = mfma16(a0, BWx[k], e0);
        }
        if (doh) {
#pragma unroll
            for (int k = 0; k < 16; ++k) {
                const f16x8 a0 = *reinterpret_cast<const f16x8*>(t0 + col * HS + (q + 4*k) * 8);
                if (k & 1) o0 = mfma16(a0, BWh[k], o0); else e0 = mfma16(a0, BWh[k], e0);
            }
        }
        const f32x4 gv = e0 + o0;
        float hv[4];
        act4(gv, gate, cc, hv);
        if (gate == 0) {
#pragma unroll
            for (int jj = 0; jj < 4; ++jj)
                hst[(q * 4 + jj) * 16 + hl] = (f16)hv[jj];
        }
        pubwave(hbuf0, flags0, grp, bb, hst, s_, 0, cci);
    };

    // ---- eng1 step for one chain: K=512 x-GEMM (h0) + K=512 h-GEMM (h1) ----
    auto comp1 = [&](const f16* t0, const f16* t1, float* cc, f16* hst,
                     int grp, int bb, int sp_, bool doh2, bool last, int cci) {
        f32x4 e0 = {bias_n, bias_n, bias_n, bias_n};
        f32x4 o0 = {0,0,0,0};
#pragma unroll
        for (int k = 0; k < 16; ++k) {
            const f16x8 a0 = *reinterpret_cast<const f16x8*>(t0 + col * HS + (q + 4*k) * 8);
            if (k & 1) o0 = mfma16(a0, BWx[k], o0); else e0 = mfma16(a0, BWx[k], e0);
        }
        if (doh2) {
#pragma unroll
            for (int k = 0; k < 16; ++k) {
                const f16x8 a0 = *reinterpret_cast<const f16x8*>(t1 + col * HS + (q + 4*k) * 8);
                if (k & 1) o0 = mfma16(a0, BWh[k], o0); else e0 = mfma16(a0, BWh[k], e0);
            }
        }
        const f32x4 gv = e0 + o0;
        float hv[4];
        act4(gv, gate, cc, hv);
        if (last) {
            if (gate == 0) {
#pragma unroll
                for (int jj = 0; jj < 4; ++jj)
                    hlast[(size_t)(bb + q * 4 + jj) * NHID + jb * 16 + hl] = hv[jj];
            }
        } else {
            if (gate == 0) {
#pragma unroll
                for (int jj = 0; jj < 4; ++jj)
                    hst[(q * 4 + jj) * 16 + hl] = (f16)hv[jj];
            }
            pubwave(hbuf1, flags1, grp, bb, hst, sp_, 1, cci);
        }
    };

    // ---- prologue: stage xT slots 0,1 for both chains ----
    if (eng == 0) {
#pragma unroll
        for (int t0 = 0; t0 < 2; ++t0) {
            const u64 vA = *reinterpret_cast<const u64*>(
                xpk + ((size_t)t0 * NBATCH + bbA + rb) * DIN + rc * 4);
            const u64 vB = *reinterpret_cast<const u64*>(
                xpk + ((size_t)t0 * NBATCH + bbB + rb) * DIN + rc * 4);
            *reinterpret_cast<u64*>(xTile[0][t0] + rb * XS + rc * 4) = vA;
            *reinterpret_cast<u64*>(xTile[1][t0] + rb * XS + rc * 4) = vB;
        }
    }
    __syncthreads();

    u64 rA[8], rB[8];
    for (int s = 0; s <= T_STEPS; ++s) {
        const bool doh0 = (s >= 1);
        const bool doh1 = (s >= 2);
        // ---- handoff chain A ----
        if (eng == 0) {
            if (doh0) { pollf(flags0, gA, s - 1); ldissue(rA, hbuf0, (s - 1) & 1, bbA); tilewr(hT0A, rA); }
        } else {
            if (doh1) { pollf(flags1, gA, s - 2); ldissue(rA, hbuf1, (s - 2) & 1, bbA); tilewr(hT1A, rA); }
        }
        __syncthreads();   // B1a: A tiles staged
        // ---- issue chain B loads (latency hides under GEMM A) ----
        if (eng == 0) {
            if (doh0) { pollf(flags0, gB_, s - 1); ldissue(rB, hbuf0, (s - 1) & 1, bbB); }
        } else {
            if (doh1) { pollf(flags1, gB_, s - 2); ldissue(rB, hbuf1, (s - 2) & 1, bbB); }
        }
        // ---- compute chain A ----
        if (eng == 0) {
            if (s < T_STEPS)
                comp0(xTile[0][s % 3], hT0A, cA, hs0[0][s & 1], gA, bbA, s, doh0, 0);
        } else {
            if (s >= 1)
                comp1(hT0A, hT1A, cA, hs1[0][(s - 1) & 1], gA, bbA, s - 1, doh1,
                      s == T_STEPS, 0);
        }
        // ---- stage chain B tiles ----
        if (eng == 0) { if (doh0) tilewr(hT0B, rB); }
        else          { if (doh1) tilewr(hT1B, rB); }
        __syncthreads();   // B1b: B tiles staged
        // ---- compute chain B (+ xT staging for s+2) ----
        if (eng == 0) {
            if (s < T_STEPS)
                comp0(xTile[1][s % 3], hT0B, cB, hs0[1][s & 1], gB_, bbB, s, doh0, 1);
            if (s + 2 < T_STEPS) {
                const u64 vA = *reinterpret_cast<const u64*>(
                    xpk + ((size_t)(s + 2) * NBATCH + bbA + rb) * DIN + rc * 4);
                const u64 vB = *reinterpret_cast<const u64*>(
                    xpk + ((size_t)(s + 2) * NBATCH + bbB + rb) * DIN + rc * 4);
                *reinterpret_cast<u64*>(xTile[0][(s + 2) % 3] + rb * XS + rc * 4) = vA;
                *reinterpret_cast<u64*>(xTile[1][(s + 2) % 3] + rb * XS + rc * 4) = vB;
            }
        } else {
            if (s >= 1)
                comp1(hT0B, hT1B, cB, hs1[1][(s - 1) & 1], gB_, bbB, s - 1, doh1,
                      s == T_STEPS, 1);
        }
        __syncthreads();   // B2
    }
}

// x [B][T][DIN] f32 -> xp [T][B][DIN] f16 (write-coalesced transpose)
__global__ void pack_x(const float* __restrict__ xin, f16* __restrict__ xp) {
    const int i = blockIdx.x * 256 + threadIdx.x;
    const long long e = (long long)i * 4;
    const int d = (int)(e & (DIN - 1));
    const int b = (int)((e >> 6) & (NBATCH - 1));
    const int t = (int)(e >> 14);
    if (t < T_STEPS) {
        const float4 v = *reinterpret_cast<const float4*>(
            xin + ((size_t)b * T_STEPS + t) * DIN + d);
        f16x4 o;
        o[0] = (f16)v.x; o[1] = (f16)v.y; o[2] = (f16)v.z; o[3] = (f16)v.w;
        *reinterpret_cast<f16x4*>(xp + ((size_t)t * NBATCH + b) * DIN + d) = o;
    }
}

__global__ void fc_kernel(const float* __restrict__ hlast, const float* __restrict__ wfc,
                          const float* __restrict__ bfc, float* __restrict__ out) {
    const int wv = threadIdx.x >> 6, l = threadIdx.x & 63;
    const int b  = blockIdx.x * 4 + wv;
    const float* hr = hlast + b * NHID;
    float s = 0.f;
#pragma unroll
    for (int j = 0; j < 8; ++j) s += hr[l + 64 * j] * wfc[l + 64 * j];
#pragma unroll
    for (int off = 32; off; off >>= 1) s += __shfl_xor(s, off, 64);
    if (l == 0) out[b] = s + bfc[0];
}

extern "C" void kernel_launch(void* const* d_in, const int* in_sizes, int n_in,
                              void* d_out, int out_size, void* d_ws, size_t ws_size,
                              hipStream_t stream) {
    const float* x    = (const float*)d_in[0];
    const float* wih0 = (const float*)d_in[1];
    const float* whh0 = (const float*)d_in[2];
    const float* bih0 = (const float*)d_in[3];
    const float* bhh0 = (const float*)d_in[4];
    const float* wih1 = (const float*)d_in[5];
    const float* whh1 = (const float*)d_in[6];
    const float* bih1 = (const float*)d_in[7];
    const float* bhh1 = (const float*)d_in[8];
    const float* wfc  = (const float*)d_in[9];
    const float* bfc  = (const float*)d_in[10];
    float* out = (float*)d_out;

    char* ws = (char*)d_ws;
    const size_t XPK_ELEMS  = (size_t)NBATCH * T_STEPS * DIN;
    const size_t FLAG_ELEMS = (size_t)NGRP2 * CBLK * FSTRIDE;   // 16384 dwords
    size_t off = 0;
    f16* xpk = (f16*)(ws + off);        off += XPK_ELEMS * 2;
    f16* hb0 = (f16*)(ws + off);        off += (size_t)2 * NBATCH * NHID * 2;
    f16* hb1 = (f16*)(ws + off);        off += (size_t)2 * NBATCH * NHID * 2;
    float* hlast = (float*)(ws + off);  off += (size_t)NBATCH * NHID * 4;
    unsigned* flg0 = (unsigned*)(ws + off); off += FLAG_ELEMS * 4;
    unsigned* flg1 = (unsigned*)(ws + off); off += FLAG_ELEMS * 4;

    // flag counters must be zero every call (graph replays!)
    hipMemsetAsync(flg0, 0, 2 * FLAG_ELEMS * 4, stream);

    pack_x<<<(int)(XPK_ELEMS / 4 / 256), 256, 0, stream>>>(x, xpk);

    {
        const f16* in0 = xpk;
        void* a[] = { (void*)&in0,
                      (void*)&wih0, (void*)&whh0, (void*)&bih0, (void*)&bhh0,
                      (void*)&wih1, (void*)&whh1, (void*)&bih1, (void*)&bhh1,
                      (void*)&hb0, (void*)&hb1, (void*)&hlast,
                      (void*)&flg0, (void*)&flg1 };
        hipLaunchCooperativeKernel(lstm_fused, dim3(256), dim3(512), a, 0, stream);
    }

    fc_kernel<<<64, 256, 0, stream>>>(hlast, wfc, bfc, out);
}